// Round 17
// baseline (974.296 us; speedup 1.0000x reference)
//
#include <hip/hip_runtime.h>

#define NB 64
#define NO 100
#define NI 2048
#define ND 16
#define NK 8

// ws layout (float offsets)
#define WS_H    0            // h_hi/h_lo (conv phase); ut [16384][64] (routing phase)
#define WS_U    9437184      // u: 64*2048*8 = 1048576
#define WS_BB   10485760     // b logits: 13107200 (pp overlaps here pre-routing)
#define WS_CB   23592960     // c: 13107200 (wB_hi/lo overlap here pre-routing)
#define WS_SP   36700160     // s partials: 100*8*64*16 = 819200
#define WS_V    38338560     // v: 102400
#define WS_PP   WS_BB        // conv2 partials: 8*64*256*64 = 8388608 floats

typedef __attribute__((ext_vector_type(8))) short bf16x8;
typedef __attribute__((ext_vector_type(16))) float f32x16;
typedef __attribute__((ext_vector_type(4))) float f32x4;

__device__ inline unsigned short f2bf(float x) {   // RNE float->bf16
    union { float f; unsigned u; } v; v.f = x;
    unsigned r = (v.u + 0x7FFFu + ((v.u >> 16) & 1u)) >> 16;
    return (unsigned short)r;
}
__device__ inline float bf2f(unsigned short h) {
    union { unsigned u; float f; } v; v.u = ((unsigned)h) << 16;
    return v.f;
}

// ---------------- conv1: [64,3,32,32] -> relu -> h_hi/h_lo bf16 ----------------
__global__ __launch_bounds__(256) void conv1_kernel(const float* __restrict__ x,
        const float* __restrict__ w, const float* __restrict__ bias,
        unsigned short* __restrict__ h_hi, unsigned short* __restrict__ h_lo) {
    const int b = blockIdx.x;
    const int ocg = blockIdx.y;
    __shared__ float xl[3 * 32 * 32];
    __shared__ float wl[16 * 243];
    const int tid = threadIdx.x;
    for (int idx = tid; idx < 3072; idx += 256) xl[idx] = x[b * 3072 + idx];
    for (int idx = tid; idx < 16 * 243; idx += 256)
        wl[idx] = w[ocg * 16 * 243 + idx];
    __syncthreads();
    const int lane = tid & 63;
    const int wg = tid >> 6;
    float acc[4][9];
    #pragma unroll
    for (int jj = 0; jj < 4; ++jj) {
        float bv = bias[ocg * 16 + wg * 4 + jj];
        #pragma unroll
        for (int j = 0; j < 9; ++j) acc[jj][j] = bv;
    }
    int xbase[9];
    #pragma unroll
    for (int j = 0; j < 9; ++j) {
        int p = lane + 64 * j;
        xbase[j] = (p / 24) * 32 + (p % 24);
    }
    for (int ic = 0; ic < 3; ++ic)
        for (int ky = 0; ky < 9; ++ky) {
            #pragma unroll
            for (int kx = 0; kx < 9; ++kx) {
                float wv[4];
                #pragma unroll
                for (int jj = 0; jj < 4; ++jj)
                    wv[jj] = wl[(wg * 4 + jj) * 243 + ic * 81 + ky * 9 + kx];
                #pragma unroll
                for (int j = 0; j < 9; ++j) {
                    float xv = xl[ic * 1024 + xbase[j] + ky * 32 + kx];
                    #pragma unroll
                    for (int jj = 0; jj < 4; ++jj)
                        acc[jj][j] = fmaf(xv, wv[jj], acc[jj][j]);
                }
            }
        }
    #pragma unroll
    for (int jj = 0; jj < 4; ++jj) {
        int oc = ocg * 16 + wg * 4 + jj;
        #pragma unroll
        for (int j = 0; j < 9; ++j) {
            int p = lane + 64 * j;
            float v = fmaxf(acc[jj][j], 0.f);
            unsigned short hi = f2bf(v);
            unsigned short lo = f2bf(v - bf2f(hi));
            size_t o = (size_t)(b * 256 + oc) * 576 + p;
            h_hi[o] = hi;
            h_lo[o] = lo;
        }
    }
}

// ---- precompute wB_hi/lo[ic][ky][oc][16] bf16 (kx 0..8, pad 9..15 = 0) ----
__global__ __launch_bounds__(256) void wb_precompute_kernel(const float* __restrict__ w,
        unsigned short* __restrict__ wBhi, unsigned short* __restrict__ wBlo) {
    const int ic = blockIdx.x;
    const int ocq = blockIdx.y;
    __shared__ float tl[64][85];
    const int tid = threadIdx.x;
    for (int f = tid; f < 5184; f += 256) {
        int oc = f / 81, kk = f % 81;
        tl[oc][kk] = w[(size_t)(ocq * 64 + oc) * 20736 + ic * 81 + kk];
    }
    __syncthreads();
    for (int idx = tid; idx < 9216; idx += 256) {
        int ky = idx >> 10;
        int rem = idx & 1023;
        int ocl = rem >> 4;
        int kx = rem & 15;
        float val = (kx < 9) ? tl[ocl][ky * 9 + kx] : 0.f;
        unsigned short hi = f2bf(val);
        unsigned short lo = f2bf(val - bf2f(hi));
        size_t dst = ((size_t)(ic * 9 + ky) * 256 + ocq * 64 + ocl) * 16 + kx;
        wBhi[dst] = hi;
        wBlo[dst] = lo;
    }
}

// -------- conv2 via MFMA (split-bf16), v5: B LDS pad-20 dbuf, A direct --------
// Wall analysis (r12-16): v1 (A+B LDS) bound by 8-way conflicts + 2 barriers
// (255us); v4 (all-global) bound by L1 return BW 52B/cyc of 64 (293us). v5:
// B staged ONCE in LDS (kills 4x redundant L1 reads), rows padded 16->20
// shorts (b64 stride-10-dword => 2-way, free per m136), double-buffered with
// ONE barrier/chunk; A direct from global (fits L1 budget, avoids LDS-pipe
// overload). Budget/CU: MFMA 92us, LDS ~90us, L1 ~35B/cyc.
__global__ __launch_bounds__(256) void conv2_mfma_kernel(
        const unsigned short* __restrict__ h_hi, const unsigned short* __restrict__ h_lo,
        const unsigned short* __restrict__ wBhi, const unsigned short* __restrict__ wBlo,
        float* __restrict__ pp) {
    const int bpair = blockIdx.x;        // 0..31
    const int ocb = blockIdx.y;          // 0..1  (128 oc)
    const int ks = blockIdx.z;           // 0..7  (32 ic)
    __shared__ __align__(16) unsigned short Bh[2][128 * 20];
    __shared__ __align__(16) unsigned short Bl[2][128 * 20];
    const int tid = threadIdx.x;
    const int lane = tid & 63;
    const int wid = tid >> 6;
    const int wr = wid >> 1, wc = wid & 1;    // wave tile 64 oc x 64 slot
    const int l31 = lane & 31, kh = lane >> 5;
    const int slot = tid & 127;               // blocal*64 + oy*8 + ox
    const int role = tid >> 7;                // 0: hi, 1: lo
    const int oy = (slot >> 3) & 7;
    const int ox = slot & 7;
    const unsigned short* hsel = role ? h_lo : h_hi;
    const size_t hrow0 = ((size_t)(bpair * 2 + (slot >> 6)) * 256) * 576;
    const int ic0 = ks * 32;
    const size_t abase = (size_t)ocb * 2048 + (size_t)(wr * 64 + l31) * 16 + kh * 8;
    const int boff0 = (wc * 64 + l31) * 20 + kh * 8;       // n=0 rows
    const int boff1 = boff0 + 32 * 20;                     // n=1 rows

    f32x16 acc[2][2];
    #pragma unroll
    for (int m = 0; m < 2; ++m)
        #pragma unroll
        for (int n = 0; n < 2; ++n)
            #pragma unroll
            for (int r = 0; r < 16; ++r) acc[m][n][r] = 0.f;

    unsigned int d0, d1, d2, d3, d4;
    bf16x8 ah0, ah1, al0, al1;

#define GLOADB(c) { const int ic_ = ic0 + (c) / 9, ky_ = (c) % 9;                          \
    const unsigned int* hp_ = (const unsigned int*)(hsel + hrow0 + (size_t)ic_ * 576       \
        + (2 * oy + ky_) * 24 + 2 * ox);                                                   \
    d0 = hp_[0]; d1 = hp_[1]; d2 = hp_[2]; d3 = hp_[3]; d4 = hp_[4]; }
#define STOREB(buf) { unsigned short* Bdst_ = (role ? Bl[buf] : Bh[buf]) + slot * 20;      \
    uint2 p0_; p0_.x = d0; p0_.y = d1;                                                     \
    uint2 p1_; p1_.x = d2; p1_.y = d3;                                                     \
    uint2 p2_; p2_.x = d4 & 0xFFFFu; p2_.y = 0u;                                           \
    uint2 p3_; p3_.x = 0u; p3_.y = 0u;                                                     \
    *(uint2*)(Bdst_) = p0_; *(uint2*)(Bdst_ + 4) = p1_;                                    \
    *(uint2*)(Bdst_ + 8) = p2_; *(uint2*)(Bdst_ + 12) = p3_; }
#define LOADA(c) { const int ic_ = ic0 + (c) / 9, ky_ = (c) % 9;                           \
    const size_t base_ = (size_t)ic_ * 36864 + (size_t)ky_ * 4096 + abase;                 \
    ah0 = *(const bf16x8*)(wBhi + base_);                                                  \
    ah1 = *(const bf16x8*)(wBhi + base_ + 512);                                            \
    al0 = *(const bf16x8*)(wBlo + base_);                                                  \
    al1 = *(const bf16x8*)(wBlo + base_ + 512); }
#define LDSB(arr, off, dst) { union { struct { uint2 a, b; } p; bf16x8 v; } u_;            \
    u_.p.a = *(const uint2*)((arr) + (off));                                               \
    u_.p.b = *(const uint2*)((arr) + (off) + 4);                                           \
    dst = u_.v; }
#define MFMA12(buf) { bf16x8 bh0, bh1, bl0, bl1;                                           \
    LDSB(Bh[buf], boff0, bh0); LDSB(Bh[buf], boff1, bh1);                                  \
    LDSB(Bl[buf], boff0, bl0); LDSB(Bl[buf], boff1, bl1);                                  \
    acc[0][0] = __builtin_amdgcn_mfma_f32_32x32x16_bf16(ah0, bh0, acc[0][0], 0, 0, 0);     \
    acc[0][0] = __builtin_amdgcn_mfma_f32_32x32x16_bf16(ah0, bl0, acc[0][0], 0, 0, 0);     \
    acc[0][0] = __builtin_amdgcn_mfma_f32_32x32x16_bf16(al0, bh0, acc[0][0], 0, 0, 0);     \
    acc[0][1] = __builtin_amdgcn_mfma_f32_32x32x16_bf16(ah0, bh1, acc[0][1], 0, 0, 0);     \
    acc[0][1] = __builtin_amdgcn_mfma_f32_32x32x16_bf16(ah0, bl1, acc[0][1], 0, 0, 0);     \
    acc[0][1] = __builtin_amdgcn_mfma_f32_32x32x16_bf16(al0, bh1, acc[0][1], 0, 0, 0);     \
    acc[1][0] = __builtin_amdgcn_mfma_f32_32x32x16_bf16(ah1, bh0, acc[1][0], 0, 0, 0);     \
    acc[1][0] = __builtin_amdgcn_mfma_f32_32x32x16_bf16(ah1, bl0, acc[1][0], 0, 0, 0);     \
    acc[1][0] = __builtin_amdgcn_mfma_f32_32x32x16_bf16(al1, bh0, acc[1][0], 0, 0, 0);     \
    acc[1][1] = __builtin_amdgcn_mfma_f32_32x32x16_bf16(ah1, bh1, acc[1][1], 0, 0, 0);     \
    acc[1][1] = __builtin_amdgcn_mfma_f32_32x32x16_bf16(ah1, bl1, acc[1][1], 0, 0, 0);     \
    acc[1][1] = __builtin_amdgcn_mfma_f32_32x32x16_bf16(al1, bh1, acc[1][1], 0, 0, 0); }

    // prologue: stage chunk 0
    GLOADB(0);
    STOREB(0);
    __syncthreads();
    #pragma unroll 1
    for (int c = 0; c < 288; ++c) {
        const int cur = c & 1;
        if (c < 287) GLOADB(c + 1);       // issue next-chunk global loads early
        LOADA(c);                          // A fragments direct from global
        MFMA12(cur);
        if (c < 287) STOREB(cur ^ 1);      // write next chunk to idle buffer
        __syncthreads();                   // single barrier per chunk
    }
#undef GLOADB
#undef STOREB
#undef LOADA
#undef LDSB
#undef MFMA12

    #pragma unroll
    for (int m = 0; m < 2; ++m)
        #pragma unroll
        for (int n = 0; n < 2; ++n) {
            const int slotg = wc * 64 + n * 32 + l31;
            const int bb = bpair * 2 + (slotg >> 6);
            const int pos = slotg & 63;
            #pragma unroll
            for (int r = 0; r < 16; ++r) {
                const int row = (r & 3) + 8 * (r >> 2) + 4 * kh;
                const int oc = ocb * 128 + wr * 64 + m * 32 + row;
                pp[(((size_t)ks * 64 + bb) * 256 + oc) * 64 + pos] = acc[m][n][r];
            }
        }
}

// -------- reduce partials over ks, +bias, squash capsule rows of 8 -> u --------
__global__ __launch_bounds__(256) void reduce_bias_squash_kernel(
        const float* __restrict__ pp, const float* __restrict__ bias,
        float* __restrict__ u) {
    const int cap = blockIdx.x * 256 + threadIdx.x;
    const int b = cap >> 11;
    const int rem = cap & 2047;
    const int oc = rem >> 3;
    const int oy = rem & 7;
    float4 sa = {0.f, 0.f, 0.f, 0.f}, sb = {0.f, 0.f, 0.f, 0.f};
    #pragma unroll
    for (int ks = 0; ks < 8; ++ks) {
        const float4* p4 = (const float4*)&pp[(((size_t)ks * 64 + b) * 256 + oc) * 64 + oy * 8];
        float4 a = p4[0], c = p4[1];
        sa.x += a.x; sa.y += a.y; sa.z += a.z; sa.w += a.w;
        sb.x += c.x; sb.y += c.y; sb.z += c.z; sb.w += c.w;
    }
    const float bv = bias[oc];
    sa.x += bv; sa.y += bv; sa.z += bv; sa.w += bv;
    sb.x += bv; sb.y += bv; sb.z += bv; sb.w += bv;
    float s2 = sa.x * sa.x + sa.y * sa.y + sa.z * sa.z + sa.w * sa.w
             + sb.x * sb.x + sb.y * sb.y + sb.z * sb.z + sb.w * sb.w;
    float scale = (s2 / (1.f + s2)) / sqrtf(s2 + 1e-8f);
    sa.x *= scale; sa.y *= scale; sa.z *= scale; sa.w *= scale;
    sb.x *= scale; sb.y *= scale; sb.z *= scale; sb.w *= scale;
    float4* up = (float4*)&u[(size_t)cap * 8];
    up[0] = sa;
    up[1] = sb;
}

// -------- transpose u -> ut[(i*8+k)][b] (once per launch; u fixed in routing) ----
__global__ __launch_bounds__(256) void transpose_u_kernel(const float* __restrict__ u,
        float* __restrict__ ut) {
    const int blk = blockIdx.x;          // 128 blocks x 128 (i,k)-rows
    __shared__ float tl[64 * 132];
    const int tid = threadIdx.x;
    #pragma unroll
    for (int rep = 0; rep < 8; ++rep) {
        const int idx = tid + 256 * rep;        // 0..2047 float4s
        const int b = idx >> 5, q = idx & 31;
        float4 uv = *(const float4*)(u + (size_t)b * 16384 + blk * 128 + 4 * q);
        *(float4*)&tl[b * 132 + 4 * q] = uv;
    }
    __syncthreads();
    #pragma unroll
    for (int rep = 0; rep < 32; ++rep) {
        const int row = rep * 4 + (tid >> 6);
        const int b = tid & 63;
        ut[(size_t)(blk * 128 + row) * 64 + b] = tl[b * 132 + row];
    }
}

// ---- r_weighted via MFMA: per-o GEMM C[16d x 64b] = W[o]^T · (c ⊙ u) ----
template <int UNIFORM>
__global__ __launch_bounds__(256) void r_weighted_mfma_kernel(
        const float* __restrict__ W, const float* __restrict__ u,
        const float* __restrict__ cbuf, float* __restrict__ sp) {
    const int o = blockIdx.x;
    const int st = blockIdx.y;
    __shared__ __align__(16) unsigned short Ahi[16 * 72];
    __shared__ __align__(16) unsigned short Alo[16 * 72];
    __shared__ __align__(16) unsigned short Bhi[64 * 72];
    __shared__ __align__(16) unsigned short Blo[64 * 72];
    const int tid = threadIdx.x;
    const int lane = tid & 63;
    const int w = tid >> 6;
    const int l15 = lane & 15;
    const int hi = lane >> 4;
    const int sb = tid >> 2;
    const int si = tid & 3;
    f32x4 acc = {0.f, 0.f, 0.f, 0.f};
    const float* Wo = W + (size_t)o * 262144;
    const int i_base = st * 256;
    #pragma unroll 1
    for (int iter = 0; iter < 32; ++iter) {
        const int i0 = i_base + iter * 8;
        __syncthreads();
        {
            float4 wv = *(const float4*)(Wo + (size_t)i0 * 128 + 4 * tid);
            const int i_l = tid >> 5;
            const int d = (tid >> 1) & 15;
            const int k0 = (tid & 1) * 4;
            unsigned short* dh = Ahi + d * 72 + i_l * 8 + k0;
            unsigned short* dl = Alo + d * 72 + i_l * 8 + k0;
            float vv[4] = {wv.x, wv.y, wv.z, wv.w};
            unsigned int h01, h23, l01, l23;
            unsigned short h, l;
            h = f2bf(vv[0]); l = f2bf(vv[0] - bf2f(h)); h01 = h; l01 = l;
            h = f2bf(vv[1]); l = f2bf(vv[1] - bf2f(h)); h01 |= (unsigned)h << 16; l01 |= (unsigned)l << 16;
            h = f2bf(vv[2]); l = f2bf(vv[2] - bf2f(h)); h23 = h; l23 = l;
            h = f2bf(vv[3]); l = f2bf(vv[3] - bf2f(h)); h23 |= (unsigned)h << 16; l23 |= (unsigned)l << 16;
            *(unsigned int*)dh = h01; *(unsigned int*)(dh + 2) = h23;
            *(unsigned int*)dl = l01; *(unsigned int*)(dl + 2) = l23;
        }
        #pragma unroll
        for (int half = 0; half < 2; ++half) {
            const int i_l = si + 4 * half;
            const float* up = u + (size_t)sb * 16384 + (size_t)(i0 + i_l) * 8;
            float4 u0 = *(const float4*)up;
            float4 u1 = *(const float4*)(up + 4);
            float cv = UNIFORM ? 0.01f
                               : cbuf[(size_t)sb * (NO * NI) + o * NI + i0 + i_l];
            float q[8] = {u0.x * cv, u0.y * cv, u0.z * cv, u0.w * cv,
                          u1.x * cv, u1.y * cv, u1.z * cv, u1.w * cv};
            uint4 ph, pl;
            unsigned short h0, h1, l0, l1;
            h0 = f2bf(q[0]); l0 = f2bf(q[0] - bf2f(h0));
            h1 = f2bf(q[1]); l1 = f2bf(q[1] - bf2f(h1));
            ph.x = h0 | ((unsigned)h1 << 16); pl.x = l0 | ((unsigned)l1 << 16);
            h0 = f2bf(q[2]); l0 = f2bf(q[2] - bf2f(h0));
            h1 = f2bf(q[3]); l1 = f2bf(q[3] - bf2f(h1));
            ph.y = h0 | ((unsigned)h1 << 16); pl.y = l0 | ((unsigned)l1 << 16);
            h0 = f2bf(q[4]); l0 = f2bf(q[4] - bf2f(h0));
            h1 = f2bf(q[5]); l1 = f2bf(q[5] - bf2f(h1));
            ph.z = h0 | ((unsigned)h1 << 16); pl.z = l0 | ((unsigned)l1 << 16);
            h0 = f2bf(q[6]); l0 = f2bf(q[6] - bf2f(h0));
            h1 = f2bf(q[7]); l1 = f2bf(q[7] - bf2f(h1));
            ph.w = h0 | ((unsigned)h1 << 16); pl.w = l0 | ((unsigned)l1 << 16);
            *(uint4*)(Bhi + sb * 72 + i_l * 8) = ph;
            *(uint4*)(Blo + sb * 72 + i_l * 8) = pl;
        }
        __syncthreads();
        #pragma unroll
        for (int ch = 0; ch < 2; ++ch) {
            bf16x8 ah = *(const bf16x8*)(Ahi + l15 * 72 + ch * 32 + hi * 8);
            bf16x8 al = *(const bf16x8*)(Alo + l15 * 72 + ch * 32 + hi * 8);
            bf16x8 bh = *(const bf16x8*)(Bhi + (w * 16 + l15) * 72 + ch * 32 + hi * 8);
            bf16x8 bl = *(const bf16x8*)(Blo + (w * 16 + l15) * 72 + ch * 32 + hi * 8);
            acc = __builtin_amdgcn_mfma_f32_16x16x32_bf16(ah, bh, acc, 0, 0, 0);
            acc = __builtin_amdgcn_mfma_f32_16x16x32_bf16(ah, bl, acc, 0, 0, 0);
            acc = __builtin_amdgcn_mfma_f32_16x16x32_bf16(al, bh, acc, 0, 0, 0);
        }
    }
    const int bg = w * 16 + l15;
    float4 st4;
    st4.x = acc[0]; st4.y = acc[1]; st4.z = acc[2]; st4.w = acc[3];
    *(float4*)&sp[(((size_t)o * 8 + st) * 64 + bg) * 16 + hi * 4] = st4;
}

// -------- reduce partials over st (8), squash over d, write v/out --------
__global__ __launch_bounds__(256) void squash_v_kernel(const float* __restrict__ sp,
        float* __restrict__ dest) {
    const int t = blockIdx.x * 256 + threadIdx.x;
    const int d = t & 15;
    const int cap = t >> 4;
    const int o = cap >> 6;
    const int bb = cap & 63;
    float s = 0.f;
    #pragma unroll
    for (int st = 0; st < 8; ++st)
        s += sp[(((size_t)o * 8 + st) * 64 + bb) * 16 + d];
    float s2 = s * s;
    #pragma unroll
    for (int off = 1; off < 16; off <<= 1)
        s2 += __shfl_xor(s2, off, 16);
    float scale = (s2 / (1.f + s2)) / sqrtf(s2 + 1e-8f);
    dest[(bb * NO + o) * ND + d] = s * scale;
}

// ---- r_logits via MFMA: per-o GEMM G[(i,k) x b] = [Wh|Wl] · [v...]; then
// in-register k-reduce with ut.
template <int ADD>
__global__ __launch_bounds__(256) void r_logits_mfma_kernel(
        const float* __restrict__ W, const float* __restrict__ ut,
        const float* __restrict__ v, float* __restrict__ bbuf) {
    const int o = blockIdx.x;
    const int st = blockIdx.y;               // 128 i per block
    __shared__ __align__(16) unsigned short Aext[128 * 40];
    __shared__ __align__(16) unsigned short B1[64 * 40];
    __shared__ __align__(16) unsigned short B2[64 * 40];
    __shared__ float ul[128 * 66];
    const int tid = threadIdx.x;
    const int lane = tid & 63;
    const int w = tid >> 6;
    const int l15 = lane & 15;
    const int hi = lane >> 4;
    const float* Wo = W + (size_t)o * 262144;
    {
        const int b = tid >> 2;
        const int dq = (tid & 3) * 4;
        float4 vv = *(const float4*)&v[((size_t)b * NO + o) * ND + dq];
        float q[4] = {vv.x, vv.y, vv.z, vv.w};
        #pragma unroll
        for (int c = 0; c < 4; ++c) {
            unsigned short h = f2bf(q[c]);
            unsigned short l = f2bf(q[c] - bf2f(h));
            B1[b * 40 + dq + c] = h;
            B1[b * 40 + 16 + dq + c] = h;
            B2[b * 40 + dq + c] = l;
            B2[b * 40 + 16 + dq + c] = 0;
        }
    }
    __syncthreads();
    #pragma unroll 1
    for (int iter = 0; iter < 8; ++iter) {
        __syncthreads();
        #pragma unroll
        for (int rep = 0; rep < 2; ++rep) {
            const int off = 4 * tid + 1024 * rep;
            float4 wv = *(const float4*)(Wo + (size_t)(st * 128 + iter * 16) * 128 + off);
            const int i_l = off >> 7;
            const int d = (off >> 3) & 15;
            const int k0 = off & 7;
            float va[4] = {wv.x, wv.y, wv.z, wv.w};
            #pragma unroll
            for (int c = 0; c < 4; ++c) {
                unsigned short h = f2bf(va[c]);
                unsigned short l = f2bf(va[c] - bf2f(h));
                const int row = i_l * 8 + k0 + c;
                Aext[row * 40 + d] = h;
                Aext[row * 40 + 16 + d] = l;
            }
        }
        const int base_row = (st * 128 + iter * 16) * 8;
        #pragma unroll
        for (int rep = 0; rep < 8; ++rep) {
            const int idx = tid + 256 * rep;
            const int row = idx >> 4, bq = idx & 15;
            float4 uv = *(const float4*)(ut + (size_t)(base_row + row) * 64 + 4 * bq);
            *(float4*)&ul[row * 66 + 4 * bq] = uv;
        }
        __syncthreads();
        f32x4 acc[8];
        bf16x8 bf1 = *(const bf16x8*)&B1[(w * 16 + l15) * 40 + hi * 8];
        bf16x8 bf2 = *(const bf16x8*)&B2[(w * 16 + l15) * 40 + hi * 8];
        #pragma unroll
        for (int mt = 0; mt < 8; ++mt) {
            f32x4 z = {0.f, 0.f, 0.f, 0.f};
            bf16x8 af = *(const bf16x8*)&Aext[(mt * 16 + l15) * 40 + hi * 8];
            z = __builtin_amdgcn_mfma_f32_16x16x32_bf16(af, bf1, z, 0, 0, 0);
            z = __builtin_amdgcn_mfma_f32_16x16x32_bf16(af, bf2, z, 0, 0, 0);
            acc[mt] = z;
        }
        #pragma unroll
        for (int mt = 0; mt < 8; ++mt) {
            float partial = 0.f;
            #pragma unroll
            for (int r = 0; r < 4; ++r) {
                const int grow = mt * 16 + hi * 4 + r;
                partial = fmaf(acc[mt][r], ul[grow * 66 + w * 16 + l15], partial);
            }
            float sum = partial + __shfl_xor(partial, 16);
            if ((hi & 1) == 0) {
                const int i_glob = st * 128 + iter * 16 + mt * 2 + (hi >> 1);
                const int bg = w * 16 + l15;
                const size_t addr = (size_t)bg * (NO * NI) + (size_t)o * NI + i_glob;
                bbuf[addr] = (ADD ? bbuf[addr] : 0.f) + sum;
            }
        }
    }
}

// -------- softmax over o (axis=1) of b -> c --------
__global__ __launch_bounds__(256) void softmax_kernel(const float* __restrict__ bbuf,
        float* __restrict__ cbuf) {
    const int bb = blockIdx.x >> 3;
    const int i = (blockIdx.x & 7) * 256 + threadIdx.x;
    const float* col = bbuf + bb * (NO * NI) + i;
    float m = -1e30f;
    for (int o = 0; o < NO; ++o) m = fmaxf(m, col[o * NI]);
    float s = 0.f;
    for (int o = 0; o < NO; ++o) s += __expf(col[o * NI] - m);
    const float inv = 1.f / s;
    float* outp = cbuf + bb * (NO * NI) + i;
    for (int o = 0; o < NO; ++o) outp[o * NI] = __expf(col[o * NI] - m) * inv;
}

extern "C" void kernel_launch(void* const* d_in, const int* in_sizes, int n_in,
                              void* d_out, int out_size, void* d_ws, size_t ws_size,
                              hipStream_t stream) {
    (void)in_sizes; (void)n_in; (void)out_size; (void)ws_size;
    const float* x      = (const float*)d_in[0];
    const float* conv_w = (const float*)d_in[1];
    const float* conv_b = (const float*)d_in[2];
    const float* pcap_w = (const float*)d_in[3];
    const float* pcap_b = (const float*)d_in[4];
    const float* W      = (const float*)d_in[5];
    float* out = (float*)d_out;
    float* ws  = (float*)d_ws;
    unsigned short* h_hi = (unsigned short*)(ws + WS_H);
    unsigned short* h_lo = h_hi + 9437184;
    unsigned short* wBhi = (unsigned short*)(ws + WS_CB);
    unsigned short* wBlo = wBhi + 9437184;
    float* ut  = ws + WS_H;    // overlaps h (dead after conv2)
    float* u   = ws + WS_U;
    float* bbf = ws + WS_BB;
    float* cbf = ws + WS_CB;
    float* sp  = ws + WS_SP;
    float* v   = ws + WS_V;
    float* pp  = ws + WS_PP;

    wb_precompute_kernel<<<dim3(256, 4), 256, 0, stream>>>(pcap_w, wBhi, wBlo);
    conv1_kernel<<<dim3(64, 16), 256, 0, stream>>>(x, conv_w, conv_b, h_hi, h_lo);
    conv2_mfma_kernel<<<dim3(32, 2, 8), 256, 0, stream>>>(h_hi, h_lo, wBhi, wBlo, pp);
    reduce_bias_squash_kernel<<<512, 256, 0, stream>>>(pp, pcap_b, u);
    transpose_u_kernel<<<128, 256, 0, stream>>>(u, ut);
    // routing iter 0 (c uniform = 1/100)
    r_weighted_mfma_kernel<1><<<dim3(100, 8), 256, 0, stream>>>(W, u, nullptr, sp);
    squash_v_kernel<<<400, 256, 0, stream>>>(sp, v);
    r_logits_mfma_kernel<0><<<dim3(100, 16), 256, 0, stream>>>(W, ut, v, bbf);
    // routing iter 1
    softmax_kernel<<<512, 256, 0, stream>>>(bbf, cbf);
    r_weighted_mfma_kernel<0><<<dim3(100, 8), 256, 0, stream>>>(W, u, cbf, sp);
    squash_v_kernel<<<400, 256, 0, stream>>>(sp, v);
    r_logits_mfma_kernel<1><<<dim3(100, 16), 256, 0, stream>>>(W, ut, v, bbf);
    // routing iter 2
    softmax_kernel<<<512, 256, 0, stream>>>(bbf, cbf);
    r_weighted_mfma_kernel<0><<<dim3(100, 8), 256, 0, stream>>>(W, u, cbf, sp);
    squash_v_kernel<<<400, 256, 0, stream>>>(sp, out);
}

// Round 18
// 827.970 us; speedup vs baseline: 1.1767x; 1.1767x over previous
//
#include <hip/hip_runtime.h>

#define NB 64
#define NO 100
#define NI 2048
#define ND 16
#define NK 8

// ws layout (float offsets)
#define WS_H    0            // h_hi/h_lo (conv phase); ut [16384][64] (routing phase)
#define WS_U    9437184      // u: 64*2048*8 = 1048576
#define WS_BB   10485760     // b logits: 13107200 (pp overlaps here pre-routing)
#define WS_CB   23592960     // c: 13107200 (wB_hi/lo overlap here pre-routing)
#define WS_SP   36700160     // s partials: 100*8*64*16 = 819200
#define WS_V    38338560     // v: 102400
#define WS_PP   WS_BB        // conv2 partials: 8*64*256*64 = 8388608 floats

typedef __attribute__((ext_vector_type(8))) short bf16x8;
typedef __attribute__((ext_vector_type(16))) float f32x16;
typedef __attribute__((ext_vector_type(4))) float f32x4;

__device__ inline unsigned short f2bf(float x) {   // RNE float->bf16
    union { float f; unsigned u; } v; v.f = x;
    unsigned r = (v.u + 0x7FFFu + ((v.u >> 16) & 1u)) >> 16;
    return (unsigned short)r;
}
__device__ inline float bf2f(unsigned short h) {
    union { unsigned u; float f; } v; v.u = ((unsigned)h) << 16;
    return v.f;
}

// ---------------- conv1: [64,3,32,32] -> relu -> h_hi/h_lo bf16 ----------------
__global__ __launch_bounds__(256) void conv1_kernel(const float* __restrict__ x,
        const float* __restrict__ w, const float* __restrict__ bias,
        unsigned short* __restrict__ h_hi, unsigned short* __restrict__ h_lo) {
    const int b = blockIdx.x;
    const int ocg = blockIdx.y;
    __shared__ float xl[3 * 32 * 32];
    __shared__ float wl[16 * 243];
    const int tid = threadIdx.x;
    for (int idx = tid; idx < 3072; idx += 256) xl[idx] = x[b * 3072 + idx];
    for (int idx = tid; idx < 16 * 243; idx += 256)
        wl[idx] = w[ocg * 16 * 243 + idx];
    __syncthreads();
    const int lane = tid & 63;
    const int wg = tid >> 6;
    float acc[4][9];
    #pragma unroll
    for (int jj = 0; jj < 4; ++jj) {
        float bv = bias[ocg * 16 + wg * 4 + jj];
        #pragma unroll
        for (int j = 0; j < 9; ++j) acc[jj][j] = bv;
    }
    int xbase[9];
    #pragma unroll
    for (int j = 0; j < 9; ++j) {
        int p = lane + 64 * j;
        xbase[j] = (p / 24) * 32 + (p % 24);
    }
    for (int ic = 0; ic < 3; ++ic)
        for (int ky = 0; ky < 9; ++ky) {
            #pragma unroll
            for (int kx = 0; kx < 9; ++kx) {
                float wv[4];
                #pragma unroll
                for (int jj = 0; jj < 4; ++jj)
                    wv[jj] = wl[(wg * 4 + jj) * 243 + ic * 81 + ky * 9 + kx];
                #pragma unroll
                for (int j = 0; j < 9; ++j) {
                    float xv = xl[ic * 1024 + xbase[j] + ky * 32 + kx];
                    #pragma unroll
                    for (int jj = 0; jj < 4; ++jj)
                        acc[jj][j] = fmaf(xv, wv[jj], acc[jj][j]);
                }
            }
        }
    #pragma unroll
    for (int jj = 0; jj < 4; ++jj) {
        int oc = ocg * 16 + wg * 4 + jj;
        #pragma unroll
        for (int j = 0; j < 9; ++j) {
            int p = lane + 64 * j;
            float v = fmaxf(acc[jj][j], 0.f);
            unsigned short hi = f2bf(v);
            unsigned short lo = f2bf(v - bf2f(hi));
            size_t o = (size_t)(b * 256 + oc) * 576 + p;
            h_hi[o] = hi;
            h_lo[o] = lo;
        }
    }
}

// ---- precompute wB_hi/lo[ic][ky][oc][16] bf16 (kx 0..8, pad 9..15 = 0) ----
__global__ __launch_bounds__(256) void wb_precompute_kernel(const float* __restrict__ w,
        unsigned short* __restrict__ wBhi, unsigned short* __restrict__ wBlo) {
    const int ic = blockIdx.x;
    const int ocq = blockIdx.y;
    __shared__ float tl[64][85];
    const int tid = threadIdx.x;
    for (int f = tid; f < 5184; f += 256) {
        int oc = f / 81, kk = f % 81;
        tl[oc][kk] = w[(size_t)(ocq * 64 + oc) * 20736 + ic * 81 + kk];
    }
    __syncthreads();
    for (int idx = tid; idx < 9216; idx += 256) {
        int ky = idx >> 10;
        int rem = idx & 1023;
        int ocl = rem >> 4;
        int kx = rem & 15;
        float val = (kx < 9) ? tl[ocl][ky * 9 + kx] : 0.f;
        unsigned short hi = f2bf(val);
        unsigned short lo = f2bf(val - bf2f(hi));
        size_t dst = ((size_t)(ic * 9 + ky) * 256 + ocq * 64 + ocl) * 16 + kx;
        wBhi[dst] = hi;
        wBlo[dst] = lo;
    }
}

// ------- conv2 via MFMA (split-bf16), v6 = r9 structure + pad-20 rows -------
// r9 (A+B LDS, 2 barriers/chunk) is the best-measured schedule (255us); its
// one defect was 2.83e7 8-way LDS conflicts from 32B rows. v6 pads tile rows
// 16->20 shorts (40B): dword-stride 10, gcd(10,32)=2 -> 2-way = free. All
// LDS accesses become paired b64 (8B-aligned). Nothing else changed.
__global__ __launch_bounds__(256) void conv2_mfma_kernel(
        const unsigned short* __restrict__ h_hi, const unsigned short* __restrict__ h_lo,
        const unsigned short* __restrict__ wBhi, const unsigned short* __restrict__ wBlo,
        float* __restrict__ pp) {
    const int bpair = blockIdx.x;        // 0..31
    const int ocb = blockIdx.y;          // 0..1  (128 oc)
    const int ks = blockIdx.z;           // 0..7  (32 ic)
    __shared__ __align__(16) unsigned short Ahi[128 * 20];
    __shared__ __align__(16) unsigned short Alo[128 * 20];
    __shared__ __align__(16) unsigned short Bhi[128 * 20];
    __shared__ __align__(16) unsigned short Blo[128 * 20];
    const int tid = threadIdx.x;
    const int lane = tid & 63;
    const int wid = tid >> 6;
    const int wr = wid >> 1, wc = wid & 1;
    const int l31 = lane & 31, kh = lane >> 5;
    const int slot = tid & 127;
    const int role = tid >> 7;
    const int oy = (slot >> 3) & 7;
    const int ox = slot & 7;
    const unsigned short* hsel = role ? h_lo : h_hi;
    const size_t hrow0 = ((size_t)(bpair * 2 + (slot >> 6)) * 256) * 576;

    f32x16 acc[2][2];
    #pragma unroll
    for (int m = 0; m < 2; ++m)
        #pragma unroll
        for (int n = 0; n < 2; ++n)
            #pragma unroll
            for (int r = 0; r < 16; ++r) acc[m][n][r] = 0.f;

#define LDS64(arr, off, dst) { union { struct { uint2 a, b; } p; bf16x8 v; } u_;           \
    u_.p.a = *(const uint2*)((arr) + (off));                                               \
    u_.p.b = *(const uint2*)((arr) + (off) + 4);                                           \
    dst = u_.v; }

    const int ic0 = ks * 32;
    for (int ic = ic0; ic < ic0 + 32; ++ic) {
        const size_t wb_ic = (size_t)ic * 36864;
        const size_t h_ic = hrow0 + (size_t)ic * 576;
        #pragma unroll 1
        for (int ky = 0; ky < 9; ++ky) {
            __syncthreads();
            // A stage: 128 oc x 16 k, source contiguous; dest rows padded to 20
            {
                const uint4* Ash = (const uint4*)(wBhi + wb_ic + (size_t)ky * 4096 + ocb * 2048);
                const uint4* Asl = (const uint4*)(wBlo + wb_ic + (size_t)ky * 4096 + ocb * 2048);
                uint4 va = Ash[tid];
                uint4 vb = Asl[tid];
                const int row = tid >> 1, half = tid & 1;
                unsigned short* dh = Ahi + row * 20 + half * 8;
                unsigned short* dl = Alo + row * 20 + half * 8;
                uint2 a0; a0.x = va.x; a0.y = va.y;
                uint2 a1; a1.x = va.z; a1.y = va.w;
                uint2 b0; b0.x = vb.x; b0.y = vb.y;
                uint2 b1; b1.x = vb.z; b1.y = vb.w;
                *(uint2*)dh = a0; *(uint2*)(dh + 4) = a1;
                *(uint2*)dl = b0; *(uint2*)(dl + 4) = b1;
            }
            // B stage: per slot read 10 bf16 window from h row, pad to 16 (rows 20)
            {
                const unsigned int* hp =
                    (const unsigned int*)(hsel + h_ic + (2 * oy + ky) * 24 + 2 * ox);
                unsigned int d0 = hp[0], d1 = hp[1], d2 = hp[2], d3 = hp[3], d4 = hp[4];
                unsigned short* Bdst = (role ? Blo : Bhi) + slot * 20;
                uint2 p0; p0.x = d0; p0.y = d1;
                uint2 p1; p1.x = d2; p1.y = d3;
                uint2 p2; p2.x = d4 & 0xFFFFu; p2.y = 0u;
                uint2 p3; p3.x = 0u; p3.y = 0u;
                *(uint2*)Bdst = p0; *(uint2*)(Bdst + 4) = p1;
                *(uint2*)(Bdst + 8) = p2; *(uint2*)(Bdst + 12) = p3;
            }
            __syncthreads();
            bf16x8 ah[2], al[2], bh[2], bl[2];
            #pragma unroll
            for (int m = 0; m < 2; ++m) {
                const int rowoff = (wr * 64 + m * 32 + l31) * 20 + kh * 8;
                LDS64(Ahi, rowoff, ah[m]);
                LDS64(Alo, rowoff, al[m]);
            }
            #pragma unroll
            for (int n = 0; n < 2; ++n) {
                const int coloff = (wc * 64 + n * 32 + l31) * 20 + kh * 8;
                LDS64(Bhi, coloff, bh[n]);
                LDS64(Blo, coloff, bl[n]);
            }
            #pragma unroll
            for (int m = 0; m < 2; ++m)
                #pragma unroll
                for (int n = 0; n < 2; ++n) {
                    acc[m][n] = __builtin_amdgcn_mfma_f32_32x32x16_bf16(
                        ah[m], bh[n], acc[m][n], 0, 0, 0);
                    acc[m][n] = __builtin_amdgcn_mfma_f32_32x32x16_bf16(
                        ah[m], bl[n], acc[m][n], 0, 0, 0);
                    acc[m][n] = __builtin_amdgcn_mfma_f32_32x32x16_bf16(
                        al[m], bh[n], acc[m][n], 0, 0, 0);
                }
        }
    }
#undef LDS64
    #pragma unroll
    for (int m = 0; m < 2; ++m)
        #pragma unroll
        for (int n = 0; n < 2; ++n) {
            const int slotg = wc * 64 + n * 32 + l31;
            const int b = bpair * 2 + (slotg >> 6);
            const int pos = slotg & 63;
            #pragma unroll
            for (int r = 0; r < 16; ++r) {
                const int row = (r & 3) + 8 * (r >> 2) + 4 * kh;
                const int oc = ocb * 128 + wr * 64 + m * 32 + row;
                pp[(((size_t)ks * 64 + b) * 256 + oc) * 64 + pos] = acc[m][n][r];
            }
        }
}

// -------- reduce partials over ks, +bias, squash capsule rows of 8 -> u --------
__global__ __launch_bounds__(256) void reduce_bias_squash_kernel(
        const float* __restrict__ pp, const float* __restrict__ bias,
        float* __restrict__ u) {
    const int cap = blockIdx.x * 256 + threadIdx.x;
    const int b = cap >> 11;
    const int rem = cap & 2047;
    const int oc = rem >> 3;
    const int oy = rem & 7;
    float4 sa = {0.f, 0.f, 0.f, 0.f}, sb = {0.f, 0.f, 0.f, 0.f};
    #pragma unroll
    for (int ks = 0; ks < 8; ++ks) {
        const float4* p4 = (const float4*)&pp[(((size_t)ks * 64 + b) * 256 + oc) * 64 + oy * 8];
        float4 a = p4[0], c = p4[1];
        sa.x += a.x; sa.y += a.y; sa.z += a.z; sa.w += a.w;
        sb.x += c.x; sb.y += c.y; sb.z += c.z; sb.w += c.w;
    }
    const float bv = bias[oc];
    sa.x += bv; sa.y += bv; sa.z += bv; sa.w += bv;
    sb.x += bv; sb.y += bv; sb.z += bv; sb.w += bv;
    float s2 = sa.x * sa.x + sa.y * sa.y + sa.z * sa.z + sa.w * sa.w
             + sb.x * sb.x + sb.y * sb.y + sb.z * sb.z + sb.w * sb.w;
    float scale = (s2 / (1.f + s2)) / sqrtf(s2 + 1e-8f);
    sa.x *= scale; sa.y *= scale; sa.z *= scale; sa.w *= scale;
    sb.x *= scale; sb.y *= scale; sb.z *= scale; sb.w *= scale;
    float4* up = (float4*)&u[(size_t)cap * 8];
    up[0] = sa;
    up[1] = sb;
}

// -------- transpose u -> ut[(i*8+k)][b] (once per launch; u fixed in routing) ----
__global__ __launch_bounds__(256) void transpose_u_kernel(const float* __restrict__ u,
        float* __restrict__ ut) {
    const int blk = blockIdx.x;          // 128 blocks x 128 (i,k)-rows
    __shared__ float tl[64 * 132];
    const int tid = threadIdx.x;
    #pragma unroll
    for (int rep = 0; rep < 8; ++rep) {
        const int idx = tid + 256 * rep;        // 0..2047 float4s
        const int b = idx >> 5, q = idx & 31;
        float4 uv = *(const float4*)(u + (size_t)b * 16384 + blk * 128 + 4 * q);
        *(float4*)&tl[b * 132 + 4 * q] = uv;
    }
    __syncthreads();
    #pragma unroll
    for (int rep = 0; rep < 32; ++rep) {
        const int row = rep * 4 + (tid >> 6);
        const int b = tid & 63;
        ut[(size_t)(blk * 128 + row) * 64 + b] = tl[b * 132 + row];
    }
}

// ---- r_weighted via MFMA: per-o GEMM C[16d x 64b] = W[o]^T · (c ⊙ u) ----
template <int UNIFORM>
__global__ __launch_bounds__(256) void r_weighted_mfma_kernel(
        const float* __restrict__ W, const float* __restrict__ u,
        const float* __restrict__ cbuf, float* __restrict__ sp) {
    const int o = blockIdx.x;
    const int st = blockIdx.y;
    __shared__ __align__(16) unsigned short Ahi[16 * 72];
    __shared__ __align__(16) unsigned short Alo[16 * 72];
    __shared__ __align__(16) unsigned short Bhi[64 * 72];
    __shared__ __align__(16) unsigned short Blo[64 * 72];
    const int tid = threadIdx.x;
    const int lane = tid & 63;
    const int w = tid >> 6;
    const int l15 = lane & 15;
    const int hi = lane >> 4;
    const int sb = tid >> 2;
    const int si = tid & 3;
    f32x4 acc = {0.f, 0.f, 0.f, 0.f};
    const float* Wo = W + (size_t)o * 262144;
    const int i_base = st * 256;
    #pragma unroll 1
    for (int iter = 0; iter < 32; ++iter) {
        const int i0 = i_base + iter * 8;
        __syncthreads();
        {
            float4 wv = *(const float4*)(Wo + (size_t)i0 * 128 + 4 * tid);
            const int i_l = tid >> 5;
            const int d = (tid >> 1) & 15;
            const int k0 = (tid & 1) * 4;
            unsigned short* dh = Ahi + d * 72 + i_l * 8 + k0;
            unsigned short* dl = Alo + d * 72 + i_l * 8 + k0;
            float vv[4] = {wv.x, wv.y, wv.z, wv.w};
            unsigned int h01, h23, l01, l23;
            unsigned short h, l;
            h = f2bf(vv[0]); l = f2bf(vv[0] - bf2f(h)); h01 = h; l01 = l;
            h = f2bf(vv[1]); l = f2bf(vv[1] - bf2f(h)); h01 |= (unsigned)h << 16; l01 |= (unsigned)l << 16;
            h = f2bf(vv[2]); l = f2bf(vv[2] - bf2f(h)); h23 = h; l23 = l;
            h = f2bf(vv[3]); l = f2bf(vv[3] - bf2f(h)); h23 |= (unsigned)h << 16; l23 |= (unsigned)l << 16;
            *(unsigned int*)dh = h01; *(unsigned int*)(dh + 2) = h23;
            *(unsigned int*)dl = l01; *(unsigned int*)(dl + 2) = l23;
        }
        #pragma unroll
        for (int half = 0; half < 2; ++half) {
            const int i_l = si + 4 * half;
            const float* up = u + (size_t)sb * 16384 + (size_t)(i0 + i_l) * 8;
            float4 u0 = *(const float4*)up;
            float4 u1 = *(const float4*)(up + 4);
            float cv = UNIFORM ? 0.01f
                               : cbuf[(size_t)sb * (NO * NI) + o * NI + i0 + i_l];
            float q[8] = {u0.x * cv, u0.y * cv, u0.z * cv, u0.w * cv,
                          u1.x * cv, u1.y * cv, u1.z * cv, u1.w * cv};
            uint4 ph, pl;
            unsigned short h0, h1, l0, l1;
            h0 = f2bf(q[0]); l0 = f2bf(q[0] - bf2f(h0));
            h1 = f2bf(q[1]); l1 = f2bf(q[1] - bf2f(h1));
            ph.x = h0 | ((unsigned)h1 << 16); pl.x = l0 | ((unsigned)l1 << 16);
            h0 = f2bf(q[2]); l0 = f2bf(q[2] - bf2f(h0));
            h1 = f2bf(q[3]); l1 = f2bf(q[3] - bf2f(h1));
            ph.y = h0 | ((unsigned)h1 << 16); pl.y = l0 | ((unsigned)l1 << 16);
            h0 = f2bf(q[4]); l0 = f2bf(q[4] - bf2f(h0));
            h1 = f2bf(q[5]); l1 = f2bf(q[5] - bf2f(h1));
            ph.z = h0 | ((unsigned)h1 << 16); pl.z = l0 | ((unsigned)l1 << 16);
            h0 = f2bf(q[6]); l0 = f2bf(q[6] - bf2f(h0));
            h1 = f2bf(q[7]); l1 = f2bf(q[7] - bf2f(h1));
            ph.w = h0 | ((unsigned)h1 << 16); pl.w = l0 | ((unsigned)l1 << 16);
            *(uint4*)(Bhi + sb * 72 + i_l * 8) = ph;
            *(uint4*)(Blo + sb * 72 + i_l * 8) = pl;
        }
        __syncthreads();
        #pragma unroll
        for (int ch = 0; ch < 2; ++ch) {
            bf16x8 ah = *(const bf16x8*)(Ahi + l15 * 72 + ch * 32 + hi * 8);
            bf16x8 al = *(const bf16x8*)(Alo + l15 * 72 + ch * 32 + hi * 8);
            bf16x8 bh = *(const bf16x8*)(Bhi + (w * 16 + l15) * 72 + ch * 32 + hi * 8);
            bf16x8 bl = *(const bf16x8*)(Blo + (w * 16 + l15) * 72 + ch * 32 + hi * 8);
            acc = __builtin_amdgcn_mfma_f32_16x16x32_bf16(ah, bh, acc, 0, 0, 0);
            acc = __builtin_amdgcn_mfma_f32_16x16x32_bf16(ah, bl, acc, 0, 0, 0);
            acc = __builtin_amdgcn_mfma_f32_16x16x32_bf16(al, bh, acc, 0, 0, 0);
        }
    }
    const int bg = w * 16 + l15;
    float4 st4;
    st4.x = acc[0]; st4.y = acc[1]; st4.z = acc[2]; st4.w = acc[3];
    *(float4*)&sp[(((size_t)o * 8 + st) * 64 + bg) * 16 + hi * 4] = st4;
}

// -------- reduce partials over st (8), squash over d, write v/out --------
__global__ __launch_bounds__(256) void squash_v_kernel(const float* __restrict__ sp,
        float* __restrict__ dest) {
    const int t = blockIdx.x * 256 + threadIdx.x;
    const int d = t & 15;
    const int cap = t >> 4;
    const int o = cap >> 6;
    const int bb = cap & 63;
    float s = 0.f;
    #pragma unroll
    for (int st = 0; st < 8; ++st)
        s += sp[(((size_t)o * 8 + st) * 64 + bb) * 16 + d];
    float s2 = s * s;
    #pragma unroll
    for (int off = 1; off < 16; off <<= 1)
        s2 += __shfl_xor(s2, off, 16);
    float scale = (s2 / (1.f + s2)) / sqrtf(s2 + 1e-8f);
    dest[(bb * NO + o) * ND + d] = s * scale;
}

// ---- r_logits via MFMA: per-o GEMM G[(i,k) x b] = [Wh|Wl] · [v...]; then
// in-register k-reduce with ut.
template <int ADD>
__global__ __launch_bounds__(256) void r_logits_mfma_kernel(
        const float* __restrict__ W, const float* __restrict__ ut,
        const float* __restrict__ v, float* __restrict__ bbuf) {
    const int o = blockIdx.x;
    const int st = blockIdx.y;               // 128 i per block
    __shared__ __align__(16) unsigned short Aext[128 * 40];
    __shared__ __align__(16) unsigned short B1[64 * 40];
    __shared__ __align__(16) unsigned short B2[64 * 40];
    __shared__ float ul[128 * 66];
    const int tid = threadIdx.x;
    const int lane = tid & 63;
    const int w = tid >> 6;
    const int l15 = lane & 15;
    const int hi = lane >> 4;
    const float* Wo = W + (size_t)o * 262144;
    {
        const int b = tid >> 2;
        const int dq = (tid & 3) * 4;
        float4 vv = *(const float4*)&v[((size_t)b * NO + o) * ND + dq];
        float q[4] = {vv.x, vv.y, vv.z, vv.w};
        #pragma unroll
        for (int c = 0; c < 4; ++c) {
            unsigned short h = f2bf(q[c]);
            unsigned short l = f2bf(q[c] - bf2f(h));
            B1[b * 40 + dq + c] = h;
            B1[b * 40 + 16 + dq + c] = h;
            B2[b * 40 + dq + c] = l;
            B2[b * 40 + 16 + dq + c] = 0;
        }
    }
    __syncthreads();
    #pragma unroll 1
    for (int iter = 0; iter < 8; ++iter) {
        __syncthreads();
        #pragma unroll
        for (int rep = 0; rep < 2; ++rep) {
            const int off = 4 * tid + 1024 * rep;
            float4 wv = *(const float4*)(Wo + (size_t)(st * 128 + iter * 16) * 128 + off);
            const int i_l = off >> 7;
            const int d = (off >> 3) & 15;
            const int k0 = off & 7;
            float va[4] = {wv.x, wv.y, wv.z, wv.w};
            #pragma unroll
            for (int c = 0; c < 4; ++c) {
                unsigned short h = f2bf(va[c]);
                unsigned short l = f2bf(va[c] - bf2f(h));
                const int row = i_l * 8 + k0 + c;
                Aext[row * 40 + d] = h;
                Aext[row * 40 + 16 + d] = l;
            }
        }
        const int base_row = (st * 128 + iter * 16) * 8;
        #pragma unroll
        for (int rep = 0; rep < 8; ++rep) {
            const int idx = tid + 256 * rep;
            const int row = idx >> 4, bq = idx & 15;
            float4 uv = *(const float4*)(ut + (size_t)(base_row + row) * 64 + 4 * bq);
            *(float4*)&ul[row * 66 + 4 * bq] = uv;
        }
        __syncthreads();
        f32x4 acc[8];
        bf16x8 bf1 = *(const bf16x8*)&B1[(w * 16 + l15) * 40 + hi * 8];
        bf16x8 bf2 = *(const bf16x8*)&B2[(w * 16 + l15) * 40 + hi * 8];
        #pragma unroll
        for (int mt = 0; mt < 8; ++mt) {
            f32x4 z = {0.f, 0.f, 0.f, 0.f};
            bf16x8 af = *(const bf16x8*)&Aext[(mt * 16 + l15) * 40 + hi * 8];
            z = __builtin_amdgcn_mfma_f32_16x16x32_bf16(af, bf1, z, 0, 0, 0);
            z = __builtin_amdgcn_mfma_f32_16x16x32_bf16(af, bf2, z, 0, 0, 0);
            acc[mt] = z;
        }
        #pragma unroll
        for (int mt = 0; mt < 8; ++mt) {
            float partial = 0.f;
            #pragma unroll
            for (int r = 0; r < 4; ++r) {
                const int grow = mt * 16 + hi * 4 + r;
                partial = fmaf(acc[mt][r], ul[grow * 66 + w * 16 + l15], partial);
            }
            float sum = partial + __shfl_xor(partial, 16);
            if ((hi & 1) == 0) {
                const int i_glob = st * 128 + iter * 16 + mt * 2 + (hi >> 1);
                const int bg = w * 16 + l15;
                const size_t addr = (size_t)bg * (NO * NI) + (size_t)o * NI + i_glob;
                bbuf[addr] = (ADD ? bbuf[addr] : 0.f) + sum;
            }
        }
    }
}

// -------- softmax over o (axis=1) of b -> c --------
__global__ __launch_bounds__(256) void softmax_kernel(const float* __restrict__ bbuf,
        float* __restrict__ cbuf) {
    const int bb = blockIdx.x >> 3;
    const int i = (blockIdx.x & 7) * 256 + threadIdx.x;
    const float* col = bbuf + bb * (NO * NI) + i;
    float m = -1e30f;
    for (int o = 0; o < NO; ++o) m = fmaxf(m, col[o * NI]);
    float s = 0.f;
    for (int o = 0; o < NO; ++o) s += __expf(col[o * NI] - m);
    const float inv = 1.f / s;
    float* outp = cbuf + bb * (NO * NI) + i;
    for (int o = 0; o < NO; ++o) outp[o * NI] = __expf(col[o * NI] - m) * inv;
}

extern "C" void kernel_launch(void* const* d_in, const int* in_sizes, int n_in,
                              void* d_out, int out_size, void* d_ws, size_t ws_size,
                              hipStream_t stream) {
    (void)in_sizes; (void)n_in; (void)out_size; (void)ws_size;
    const float* x      = (const float*)d_in[0];
    const float* conv_w = (const float*)d_in[1];
    const float* conv_b = (const float*)d_in[2];
    const float* pcap_w = (const float*)d_in[3];
    const float* pcap_b = (const float*)d_in[4];
    const float* W      = (const float*)d_in[5];
    float* out = (float*)d_out;
    float* ws  = (float*)d_ws;
    unsigned short* h_hi = (unsigned short*)(ws + WS_H);
    unsigned short* h_lo = h_hi + 9437184;
    unsigned short* wBhi = (unsigned short*)(ws + WS_CB);
    unsigned short* wBlo = wBhi + 9437184;
    float* ut  = ws + WS_H;    // overlaps h (dead after conv2)
    float* u   = ws + WS_U;
    float* bbf = ws + WS_BB;
    float* cbf = ws + WS_CB;
    float* sp  = ws + WS_SP;
    float* v   = ws + WS_V;
    float* pp  = ws + WS_PP;

    wb_precompute_kernel<<<dim3(256, 4), 256, 0, stream>>>(pcap_w, wBhi, wBlo);
    conv1_kernel<<<dim3(64, 16), 256, 0, stream>>>(x, conv_w, conv_b, h_hi, h_lo);
    conv2_mfma_kernel<<<dim3(32, 2, 8), 256, 0, stream>>>(h_hi, h_lo, wBhi, wBlo, pp);
    reduce_bias_squash_kernel<<<512, 256, 0, stream>>>(pp, pcap_b, u);
    transpose_u_kernel<<<128, 256, 0, stream>>>(u, ut);
    // routing iter 0 (c uniform = 1/100)
    r_weighted_mfma_kernel<1><<<dim3(100, 8), 256, 0, stream>>>(W, u, nullptr, sp);
    squash_v_kernel<<<400, 256, 0, stream>>>(sp, v);
    r_logits_mfma_kernel<0><<<dim3(100, 16), 256, 0, stream>>>(W, ut, v, bbf);
    // routing iter 1
    softmax_kernel<<<512, 256, 0, stream>>>(bbf, cbf);
    r_weighted_mfma_kernel<0><<<dim3(100, 8), 256, 0, stream>>>(W, u, cbf, sp);
    squash_v_kernel<<<400, 256, 0, stream>>>(sp, v);
    r_logits_mfma_kernel<1><<<dim3(100, 16), 256, 0, stream>>>(W, ut, v, bbf);
    // routing iter 2
    softmax_kernel<<<512, 256, 0, stream>>>(bbf, cbf);
    r_weighted_mfma_kernel<0><<<dim3(100, 8), 256, 0, stream>>>(W, u, cbf, sp);
    squash_v_kernel<<<400, 256, 0, stream>>>(sp, out);
}

// Round 19
// 825.270 us; speedup vs baseline: 1.1806x; 1.0033x over previous
//
#include <hip/hip_runtime.h>

#define NB 64
#define NO 100
#define NI 2048
#define ND 16
#define NK 8

// ws layout (float offsets)
#define WS_H    0            // h_hi/h_lo (conv phase); ut [16384][64] (routing phase)
#define WS_U    9437184      // u: 64*2048*8 = 1048576
#define WS_BB   10485760     // b logits: 13107200 (pp overlaps here pre-routing)
#define WS_CB   23592960     // c: 13107200 (wB_hi/lo overlap here pre-routing)
#define WS_SP   36700160     // s partials: 100*8*64*16 = 819200
#define WS_V    38338560     // v: 102400
#define WS_PP   WS_BB        // conv2 partials: 8*64*256*64 = 8388608 floats

typedef __attribute__((ext_vector_type(8))) short bf16x8;
typedef __attribute__((ext_vector_type(16))) float f32x16;
typedef __attribute__((ext_vector_type(4))) float f32x4;

__device__ inline unsigned short f2bf(float x) {   // RNE float->bf16
    union { float f; unsigned u; } v; v.f = x;
    unsigned r = (v.u + 0x7FFFu + ((v.u >> 16) & 1u)) >> 16;
    return (unsigned short)r;
}
__device__ inline float bf2f(unsigned short h) {
    union { unsigned u; float f; } v; v.u = ((unsigned)h) << 16;
    return v.f;
}

// ---------------- conv1: [64,3,32,32] -> relu -> h_hi/h_lo bf16 ----------------
__global__ __launch_bounds__(256) void conv1_kernel(const float* __restrict__ x,
        const float* __restrict__ w, const float* __restrict__ bias,
        unsigned short* __restrict__ h_hi, unsigned short* __restrict__ h_lo) {
    const int b = blockIdx.x;
    const int ocg = blockIdx.y;
    __shared__ float xl[3 * 32 * 32];
    __shared__ float wl[16 * 243];
    const int tid = threadIdx.x;
    for (int idx = tid; idx < 3072; idx += 256) xl[idx] = x[b * 3072 + idx];
    for (int idx = tid; idx < 16 * 243; idx += 256)
        wl[idx] = w[ocg * 16 * 243 + idx];
    __syncthreads();
    const int lane = tid & 63;
    const int wg = tid >> 6;
    float acc[4][9];
    #pragma unroll
    for (int jj = 0; jj < 4; ++jj) {
        float bv = bias[ocg * 16 + wg * 4 + jj];
        #pragma unroll
        for (int j = 0; j < 9; ++j) acc[jj][j] = bv;
    }
    int xbase[9];
    #pragma unroll
    for (int j = 0; j < 9; ++j) {
        int p = lane + 64 * j;
        xbase[j] = (p / 24) * 32 + (p % 24);
    }
    for (int ic = 0; ic < 3; ++ic)
        for (int ky = 0; ky < 9; ++ky) {
            #pragma unroll
            for (int kx = 0; kx < 9; ++kx) {
                float wv[4];
                #pragma unroll
                for (int jj = 0; jj < 4; ++jj)
                    wv[jj] = wl[(wg * 4 + jj) * 243 + ic * 81 + ky * 9 + kx];
                #pragma unroll
                for (int j = 0; j < 9; ++j) {
                    float xv = xl[ic * 1024 + xbase[j] + ky * 32 + kx];
                    #pragma unroll
                    for (int jj = 0; jj < 4; ++jj)
                        acc[jj][j] = fmaf(xv, wv[jj], acc[jj][j]);
                }
            }
        }
    #pragma unroll
    for (int jj = 0; jj < 4; ++jj) {
        int oc = ocg * 16 + wg * 4 + jj;
        #pragma unroll
        for (int j = 0; j < 9; ++j) {
            int p = lane + 64 * j;
            float v = fmaxf(acc[jj][j], 0.f);
            unsigned short hi = f2bf(v);
            unsigned short lo = f2bf(v - bf2f(hi));
            size_t o = (size_t)(b * 256 + oc) * 576 + p;
            h_hi[o] = hi;
            h_lo[o] = lo;
        }
    }
}

// ---- precompute wB_hi/lo[ic][ky][oc][16] bf16 (kx 0..8, pad 9..15 = 0) ----
__global__ __launch_bounds__(256) void wb_precompute_kernel(const float* __restrict__ w,
        unsigned short* __restrict__ wBhi, unsigned short* __restrict__ wBlo) {
    const int ic = blockIdx.x;
    const int ocq = blockIdx.y;
    __shared__ float tl[64][85];
    const int tid = threadIdx.x;
    for (int f = tid; f < 5184; f += 256) {
        int oc = f / 81, kk = f % 81;
        tl[oc][kk] = w[(size_t)(ocq * 64 + oc) * 20736 + ic * 81 + kk];
    }
    __syncthreads();
    for (int idx = tid; idx < 9216; idx += 256) {
        int ky = idx >> 10;
        int rem = idx & 1023;
        int ocl = rem >> 4;
        int kx = rem & 15;
        float val = (kx < 9) ? tl[ocl][ky * 9 + kx] : 0.f;
        unsigned short hi = f2bf(val);
        unsigned short lo = f2bf(val - bf2f(hi));
        size_t dst = ((size_t)(ic * 9 + ky) * 256 + ocq * 64 + ocl) * 16 + kx;
        wBhi[dst] = hi;
        wBlo[dst] = lo;
    }
}

// ------- conv2 via MFMA (split-bf16), v6 = r9 structure + pad-20 rows -------
// Best-measured schedule (248us, MfmaUtil 42%); conflicts 2.8e7 -> 9.4e6 via
// 40B rows (gcd(10,32)=2 -> 2-way = free). Equilibrium confirmed; frozen.
__global__ __launch_bounds__(256) void conv2_mfma_kernel(
        const unsigned short* __restrict__ h_hi, const unsigned short* __restrict__ h_lo,
        const unsigned short* __restrict__ wBhi, const unsigned short* __restrict__ wBlo,
        float* __restrict__ pp) {
    const int bpair = blockIdx.x;        // 0..31
    const int ocb = blockIdx.y;          // 0..1  (128 oc)
    const int ks = blockIdx.z;           // 0..7  (32 ic)
    __shared__ __align__(16) unsigned short Ahi[128 * 20];
    __shared__ __align__(16) unsigned short Alo[128 * 20];
    __shared__ __align__(16) unsigned short Bhi[128 * 20];
    __shared__ __align__(16) unsigned short Blo[128 * 20];
    const int tid = threadIdx.x;
    const int lane = tid & 63;
    const int wid = tid >> 6;
    const int wr = wid >> 1, wc = wid & 1;
    const int l31 = lane & 31, kh = lane >> 5;
    const int slot = tid & 127;
    const int role = tid >> 7;
    const int oy = (slot >> 3) & 7;
    const int ox = slot & 7;
    const unsigned short* hsel = role ? h_lo : h_hi;
    const size_t hrow0 = ((size_t)(bpair * 2 + (slot >> 6)) * 256) * 576;

    f32x16 acc[2][2];
    #pragma unroll
    for (int m = 0; m < 2; ++m)
        #pragma unroll
        for (int n = 0; n < 2; ++n)
            #pragma unroll
            for (int r = 0; r < 16; ++r) acc[m][n][r] = 0.f;

#define LDS64(arr, off, dst) { union { struct { uint2 a, b; } p; bf16x8 v; } u_;           \
    u_.p.a = *(const uint2*)((arr) + (off));                                               \
    u_.p.b = *(const uint2*)((arr) + (off) + 4);                                           \
    dst = u_.v; }

    const int ic0 = ks * 32;
    for (int ic = ic0; ic < ic0 + 32; ++ic) {
        const size_t wb_ic = (size_t)ic * 36864;
        const size_t h_ic = hrow0 + (size_t)ic * 576;
        #pragma unroll 1
        for (int ky = 0; ky < 9; ++ky) {
            __syncthreads();
            // A stage: 128 oc x 16 k, source contiguous; dest rows padded to 20
            {
                const uint4* Ash = (const uint4*)(wBhi + wb_ic + (size_t)ky * 4096 + ocb * 2048);
                const uint4* Asl = (const uint4*)(wBlo + wb_ic + (size_t)ky * 4096 + ocb * 2048);
                uint4 va = Ash[tid];
                uint4 vb = Asl[tid];
                const int row = tid >> 1, half = tid & 1;
                unsigned short* dh = Ahi + row * 20 + half * 8;
                unsigned short* dl = Alo + row * 20 + half * 8;
                uint2 a0; a0.x = va.x; a0.y = va.y;
                uint2 a1; a1.x = va.z; a1.y = va.w;
                uint2 b0; b0.x = vb.x; b0.y = vb.y;
                uint2 b1; b1.x = vb.z; b1.y = vb.w;
                *(uint2*)dh = a0; *(uint2*)(dh + 4) = a1;
                *(uint2*)dl = b0; *(uint2*)(dl + 4) = b1;
            }
            // B stage: per slot read 10 bf16 window from h row, pad to 16 (rows 20)
            {
                const unsigned int* hp =
                    (const unsigned int*)(hsel + h_ic + (2 * oy + ky) * 24 + 2 * ox);
                unsigned int d0 = hp[0], d1 = hp[1], d2 = hp[2], d3 = hp[3], d4 = hp[4];
                unsigned short* Bdst = (role ? Blo : Bhi) + slot * 20;
                uint2 p0; p0.x = d0; p0.y = d1;
                uint2 p1; p1.x = d2; p1.y = d3;
                uint2 p2; p2.x = d4 & 0xFFFFu; p2.y = 0u;
                uint2 p3; p3.x = 0u; p3.y = 0u;
                *(uint2*)Bdst = p0; *(uint2*)(Bdst + 4) = p1;
                *(uint2*)(Bdst + 8) = p2; *(uint2*)(Bdst + 12) = p3;
            }
            __syncthreads();
            bf16x8 ah[2], al[2], bh[2], bl[2];
            #pragma unroll
            for (int m = 0; m < 2; ++m) {
                const int rowoff = (wr * 64 + m * 32 + l31) * 20 + kh * 8;
                LDS64(Ahi, rowoff, ah[m]);
                LDS64(Alo, rowoff, al[m]);
            }
            #pragma unroll
            for (int n = 0; n < 2; ++n) {
                const int coloff = (wc * 64 + n * 32 + l31) * 20 + kh * 8;
                LDS64(Bhi, coloff, bh[n]);
                LDS64(Blo, coloff, bl[n]);
            }
            #pragma unroll
            for (int m = 0; m < 2; ++m)
                #pragma unroll
                for (int n = 0; n < 2; ++n) {
                    acc[m][n] = __builtin_amdgcn_mfma_f32_32x32x16_bf16(
                        ah[m], bh[n], acc[m][n], 0, 0, 0);
                    acc[m][n] = __builtin_amdgcn_mfma_f32_32x32x16_bf16(
                        ah[m], bl[n], acc[m][n], 0, 0, 0);
                    acc[m][n] = __builtin_amdgcn_mfma_f32_32x32x16_bf16(
                        al[m], bh[n], acc[m][n], 0, 0, 0);
                }
        }
    }
#undef LDS64
    #pragma unroll
    for (int m = 0; m < 2; ++m)
        #pragma unroll
        for (int n = 0; n < 2; ++n) {
            const int slotg = wc * 64 + n * 32 + l31;
            const int b = bpair * 2 + (slotg >> 6);
            const int pos = slotg & 63;
            #pragma unroll
            for (int r = 0; r < 16; ++r) {
                const int row = (r & 3) + 8 * (r >> 2) + 4 * kh;
                const int oc = ocb * 128 + wr * 64 + m * 32 + row;
                pp[(((size_t)ks * 64 + b) * 256 + oc) * 64 + pos] = acc[m][n][r];
            }
        }
}

// -------- reduce partials over ks, +bias, squash capsule rows of 8 -> u --------
__global__ __launch_bounds__(256) void reduce_bias_squash_kernel(
        const float* __restrict__ pp, const float* __restrict__ bias,
        float* __restrict__ u) {
    const int cap = blockIdx.x * 256 + threadIdx.x;
    const int b = cap >> 11;
    const int rem = cap & 2047;
    const int oc = rem >> 3;
    const int oy = rem & 7;
    float4 sa = {0.f, 0.f, 0.f, 0.f}, sb = {0.f, 0.f, 0.f, 0.f};
    #pragma unroll
    for (int ks = 0; ks < 8; ++ks) {
        const float4* p4 = (const float4*)&pp[(((size_t)ks * 64 + b) * 256 + oc) * 64 + oy * 8];
        float4 a = p4[0], c = p4[1];
        sa.x += a.x; sa.y += a.y; sa.z += a.z; sa.w += a.w;
        sb.x += c.x; sb.y += c.y; sb.z += c.z; sb.w += c.w;
    }
    const float bv = bias[oc];
    sa.x += bv; sa.y += bv; sa.z += bv; sa.w += bv;
    sb.x += bv; sb.y += bv; sb.z += bv; sb.w += bv;
    float s2 = sa.x * sa.x + sa.y * sa.y + sa.z * sa.z + sa.w * sa.w
             + sb.x * sb.x + sb.y * sb.y + sb.z * sb.z + sb.w * sb.w;
    float scale = (s2 / (1.f + s2)) / sqrtf(s2 + 1e-8f);
    sa.x *= scale; sa.y *= scale; sa.z *= scale; sa.w *= scale;
    sb.x *= scale; sb.y *= scale; sb.z *= scale; sb.w *= scale;
    float4* up = (float4*)&u[(size_t)cap * 8];
    up[0] = sa;
    up[1] = sb;
}

// -------- transpose u -> ut[(i*8+k)][b] (once per launch; u fixed in routing) ----
__global__ __launch_bounds__(256) void transpose_u_kernel(const float* __restrict__ u,
        float* __restrict__ ut) {
    const int blk = blockIdx.x;          // 128 blocks x 128 (i,k)-rows
    __shared__ float tl[64 * 132];
    const int tid = threadIdx.x;
    #pragma unroll
    for (int rep = 0; rep < 8; ++rep) {
        const int idx = tid + 256 * rep;        // 0..2047 float4s
        const int b = idx >> 5, q = idx & 31;
        float4 uv = *(const float4*)(u + (size_t)b * 16384 + blk * 128 + 4 * q);
        *(float4*)&tl[b * 132 + 4 * q] = uv;
    }
    __syncthreads();
    #pragma unroll
    for (int rep = 0; rep < 32; ++rep) {
        const int row = rep * 4 + (tid >> 6);
        const int b = tid & 63;
        ut[(size_t)(blk * 128 + row) * 64 + b] = tl[b * 132 + row];
    }
}

// ---- r_weighted via MFMA: per-o GEMM C[16d x 64b] = W[o]^T · (c ⊙ u) ----
template <int UNIFORM>
__global__ __launch_bounds__(256) void r_weighted_mfma_kernel(
        const float* __restrict__ W, const float* __restrict__ u,
        const float* __restrict__ cbuf, float* __restrict__ sp) {
    const int o = blockIdx.x;
    const int st = blockIdx.y;
    __shared__ __align__(16) unsigned short Ahi[16 * 72];
    __shared__ __align__(16) unsigned short Alo[16 * 72];
    __shared__ __align__(16) unsigned short Bhi[64 * 72];
    __shared__ __align__(16) unsigned short Blo[64 * 72];
    const int tid = threadIdx.x;
    const int lane = tid & 63;
    const int w = tid >> 6;
    const int l15 = lane & 15;
    const int hi = lane >> 4;
    const int sb = tid >> 2;
    const int si = tid & 3;
    f32x4 acc = {0.f, 0.f, 0.f, 0.f};
    const float* Wo = W + (size_t)o * 262144;
    const int i_base = st * 256;
    #pragma unroll 1
    for (int iter = 0; iter < 32; ++iter) {
        const int i0 = i_base + iter * 8;
        __syncthreads();
        {
            float4 wv = *(const float4*)(Wo + (size_t)i0 * 128 + 4 * tid);
            const int i_l = tid >> 5;
            const int d = (tid >> 1) & 15;
            const int k0 = (tid & 1) * 4;
            unsigned short* dh = Ahi + d * 72 + i_l * 8 + k0;
            unsigned short* dl = Alo + d * 72 + i_l * 8 + k0;
            float vv[4] = {wv.x, wv.y, wv.z, wv.w};
            unsigned int h01, h23, l01, l23;
            unsigned short h, l;
            h = f2bf(vv[0]); l = f2bf(vv[0] - bf2f(h)); h01 = h; l01 = l;
            h = f2bf(vv[1]); l = f2bf(vv[1] - bf2f(h)); h01 |= (unsigned)h << 16; l01 |= (unsigned)l << 16;
            h = f2bf(vv[2]); l = f2bf(vv[2] - bf2f(h)); h23 = h; l23 = l;
            h = f2bf(vv[3]); l = f2bf(vv[3] - bf2f(h)); h23 |= (unsigned)h << 16; l23 |= (unsigned)l << 16;
            *(unsigned int*)dh = h01; *(unsigned int*)(dh + 2) = h23;
            *(unsigned int*)dl = l01; *(unsigned int*)(dl + 2) = l23;
        }
        #pragma unroll
        for (int half = 0; half < 2; ++half) {
            const int i_l = si + 4 * half;
            const float* up = u + (size_t)sb * 16384 + (size_t)(i0 + i_l) * 8;
            float4 u0 = *(const float4*)up;
            float4 u1 = *(const float4*)(up + 4);
            float cv = UNIFORM ? 0.01f
                               : cbuf[(size_t)sb * (NO * NI) + o * NI + i0 + i_l];
            float q[8] = {u0.x * cv, u0.y * cv, u0.z * cv, u0.w * cv,
                          u1.x * cv, u1.y * cv, u1.z * cv, u1.w * cv};
            uint4 ph, pl;
            unsigned short h0, h1, l0, l1;
            h0 = f2bf(q[0]); l0 = f2bf(q[0] - bf2f(h0));
            h1 = f2bf(q[1]); l1 = f2bf(q[1] - bf2f(h1));
            ph.x = h0 | ((unsigned)h1 << 16); pl.x = l0 | ((unsigned)l1 << 16);
            h0 = f2bf(q[2]); l0 = f2bf(q[2] - bf2f(h0));
            h1 = f2bf(q[3]); l1 = f2bf(q[3] - bf2f(h1));
            ph.y = h0 | ((unsigned)h1 << 16); pl.y = l0 | ((unsigned)l1 << 16);
            h0 = f2bf(q[4]); l0 = f2bf(q[4] - bf2f(h0));
            h1 = f2bf(q[5]); l1 = f2bf(q[5] - bf2f(h1));
            ph.z = h0 | ((unsigned)h1 << 16); pl.z = l0 | ((unsigned)l1 << 16);
            h0 = f2bf(q[6]); l0 = f2bf(q[6] - bf2f(h0));
            h1 = f2bf(q[7]); l1 = f2bf(q[7] - bf2f(h1));
            ph.w = h0 | ((unsigned)h1 << 16); pl.w = l0 | ((unsigned)l1 << 16);
            *(uint4*)(Bhi + sb * 72 + i_l * 8) = ph;
            *(uint4*)(Blo + sb * 72 + i_l * 8) = pl;
        }
        __syncthreads();
        #pragma unroll
        for (int ch = 0; ch < 2; ++ch) {
            bf16x8 ah = *(const bf16x8*)(Ahi + l15 * 72 + ch * 32 + hi * 8);
            bf16x8 al = *(const bf16x8*)(Alo + l15 * 72 + ch * 32 + hi * 8);
            bf16x8 bh = *(const bf16x8*)(Bhi + (w * 16 + l15) * 72 + ch * 32 + hi * 8);
            bf16x8 bl = *(const bf16x8*)(Blo + (w * 16 + l15) * 72 + ch * 32 + hi * 8);
            acc = __builtin_amdgcn_mfma_f32_16x16x32_bf16(ah, bh, acc, 0, 0, 0);
            acc = __builtin_amdgcn_mfma_f32_16x16x32_bf16(ah, bl, acc, 0, 0, 0);
            acc = __builtin_amdgcn_mfma_f32_16x16x32_bf16(al, bh, acc, 0, 0, 0);
        }
    }
    const int bg = w * 16 + l15;
    float4 st4;
    st4.x = acc[0]; st4.y = acc[1]; st4.z = acc[2]; st4.w = acc[3];
    *(float4*)&sp[(((size_t)o * 8 + st) * 64 + bg) * 16 + hi * 4] = st4;
}

// -------- reduce partials over st (8), squash over d, write v/out --------
__global__ __launch_bounds__(256) void squash_v_kernel(const float* __restrict__ sp,
        float* __restrict__ dest) {
    const int t = blockIdx.x * 256 + threadIdx.x;
    const int d = t & 15;
    const int cap = t >> 4;
    const int o = cap >> 6;
    const int bb = cap & 63;
    float s = 0.f;
    #pragma unroll
    for (int st = 0; st < 8; ++st)
        s += sp[(((size_t)o * 8 + st) * 64 + bb) * 16 + d];
    float s2 = s * s;
    #pragma unroll
    for (int off = 1; off < 16; off <<= 1)
        s2 += __shfl_xor(s2, off, 16);
    float scale = (s2 / (1.f + s2)) / sqrtf(s2 + 1e-8f);
    dest[(bb * NO + o) * ND + d] = s * scale;
}

// ---- r_logits via MFMA: per-o GEMM G[(i,k) x b] = [Wh|Wl] · [v...]; then
// in-register k-reduce with ut. A-stage vectorized (r18 post-mortem: 16
// scalar b16 LDS writes/thread/iter were the staging wall): thread slot =
// (i_l<<5)|(dgrp<<3)|k loads 4 d-strided dwords (k-coalesced 32B segments),
// packs 4 shorts/plane, writes 2x b64 instead of 8x b16.
template <int ADD>
__global__ __launch_bounds__(256) void r_logits_mfma_kernel(
        const float* __restrict__ W, const float* __restrict__ ut,
        const float* __restrict__ v, float* __restrict__ bbuf) {
    const int o = blockIdx.x;
    const int st = blockIdx.y;               // 128 i per block
    __shared__ __align__(16) unsigned short Aext[128 * 40];
    __shared__ __align__(16) unsigned short B1[64 * 40];
    __shared__ __align__(16) unsigned short B2[64 * 40];
    __shared__ float ul[128 * 66];
    const int tid = threadIdx.x;
    const int lane = tid & 63;
    const int w = tid >> 6;
    const int l15 = lane & 15;
    const int hi = lane >> 4;
    const float* Wo = W + (size_t)o * 262144;
    {
        const int b = tid >> 2;
        const int dq = (tid & 3) * 4;
        float4 vv = *(const float4*)&v[((size_t)b * NO + o) * ND + dq];
        float q[4] = {vv.x, vv.y, vv.z, vv.w};
        #pragma unroll
        for (int c = 0; c < 4; ++c) {
            unsigned short h = f2bf(q[c]);
            unsigned short l = f2bf(q[c] - bf2f(h));
            B1[b * 40 + dq + c] = h;
            B1[b * 40 + 16 + dq + c] = h;
            B2[b * 40 + dq + c] = l;
            B2[b * 40 + 16 + dq + c] = 0;
        }
    }
    __syncthreads();
    #pragma unroll 1
    for (int iter = 0; iter < 8; ++iter) {
        __syncthreads();
        // A stage (vectorized): 512 slots = 16 i x 4 dgrp x 8 k
        #pragma unroll
        for (int rep = 0; rep < 2; ++rep) {
            const int slot = rep * 256 + tid;
            const int i_l = slot >> 5;
            const int dgrp = (slot >> 3) & 3;
            const int k = slot & 7;
            const float* src = Wo + (size_t)(st * 128 + iter * 16 + i_l) * 128
                             + dgrp * 32 + k;
            float v0 = src[0], v1 = src[8], v2 = src[16], v3 = src[24];
            unsigned short h0 = f2bf(v0), l0 = f2bf(v0 - bf2f(h0));
            unsigned short h1 = f2bf(v1), l1 = f2bf(v1 - bf2f(h1));
            unsigned short h2 = f2bf(v2), l2 = f2bf(v2 - bf2f(h2));
            unsigned short h3 = f2bf(v3), l3 = f2bf(v3 - bf2f(h3));
            uint2 ph; ph.x = h0 | ((unsigned)h1 << 16); ph.y = h2 | ((unsigned)h3 << 16);
            uint2 pl; pl.x = l0 | ((unsigned)l1 << 16); pl.y = l2 | ((unsigned)l3 << 16);
            unsigned short* dst = Aext + (i_l * 8 + k) * 40 + dgrp * 4;
            *(uint2*)dst = ph;
            *(uint2*)(dst + 16) = pl;
        }
        const int base_row = (st * 128 + iter * 16) * 8;
        #pragma unroll
        for (int rep = 0; rep < 8; ++rep) {
            const int idx = tid + 256 * rep;
            const int row = idx >> 4, bq = idx & 15;
            float4 uv = *(const float4*)(ut + (size_t)(base_row + row) * 64 + 4 * bq);
            *(float4*)&ul[row * 66 + 4 * bq] = uv;
        }
        __syncthreads();
        f32x4 acc[8];
        bf16x8 bf1 = *(const bf16x8*)&B1[(w * 16 + l15) * 40 + hi * 8];
        bf16x8 bf2 = *(const bf16x8*)&B2[(w * 16 + l15) * 40 + hi * 8];
        #pragma unroll
        for (int mt = 0; mt < 8; ++mt) {
            f32x4 z = {0.f, 0.f, 0.f, 0.f};
            bf16x8 af = *(const bf16x8*)&Aext[(mt * 16 + l15) * 40 + hi * 8];
            z = __builtin_amdgcn_mfma_f32_16x16x32_bf16(af, bf1, z, 0, 0, 0);
            z = __builtin_amdgcn_mfma_f32_16x16x32_bf16(af, bf2, z, 0, 0, 0);
            acc[mt] = z;
        }
        #pragma unroll
        for (int mt = 0; mt < 8; ++mt) {
            float partial = 0.f;
            #pragma unroll
            for (int r = 0; r < 4; ++r) {
                const int grow = mt * 16 + hi * 4 + r;
                partial = fmaf(acc[mt][r], ul[grow * 66 + w * 16 + l15], partial);
            }
            float sum = partial + __shfl_xor(partial, 16);
            if ((hi & 1) == 0) {
                const int i_glob = st * 128 + iter * 16 + mt * 2 + (hi >> 1);
                const int bg = w * 16 + l15;
                const size_t addr = (size_t)bg * (NO * NI) + (size_t)o * NI + i_glob;
                bbuf[addr] = (ADD ? bbuf[addr] : 0.f) + sum;
            }
        }
    }
}

// -------- softmax over o (axis=1) of b -> c --------
__global__ __launch_bounds__(256) void softmax_kernel(const float* __restrict__ bbuf,
        float* __restrict__ cbuf) {
    const int bb = blockIdx.x >> 3;
    const int i = (blockIdx.x & 7) * 256 + threadIdx.x;
    const float* col = bbuf + bb * (NO * NI) + i;
    float m = -1e30f;
    for (int o = 0; o < NO; ++o) m = fmaxf(m, col[o * NI]);
    float s = 0.f;
    for (int o = 0; o < NO; ++o) s += __expf(col[o * NI] - m);
    const float inv = 1.f / s;
    float* outp = cbuf + bb * (NO * NI) + i;
    for (int o = 0; o < NO; ++o) outp[o * NI] = __expf(col[o * NI] - m) * inv;
}

extern "C" void kernel_launch(void* const* d_in, const int* in_sizes, int n_in,
                              void* d_out, int out_size, void* d_ws, size_t ws_size,
                              hipStream_t stream) {
    (void)in_sizes; (void)n_in; (void)out_size; (void)ws_size;
    const float* x      = (const float*)d_in[0];
    const float* conv_w = (const float*)d_in[1];
    const float* conv_b = (const float*)d_in[2];
    const float* pcap_w = (const float*)d_in[3];
    const float* pcap_b = (const float*)d_in[4];
    const float* W      = (const float*)d_in[5];
    float* out = (float*)d_out;
    float* ws  = (float*)d_ws;
    unsigned short* h_hi = (unsigned short*)(ws + WS_H);
    unsigned short* h_lo = h_hi + 9437184;
    unsigned short* wBhi = (unsigned short*)(ws + WS_CB);
    unsigned short* wBlo = wBhi + 9437184;
    float* ut  = ws + WS_H;    // overlaps h (dead after conv2)
    float* u   = ws + WS_U;
    float* bbf = ws + WS_BB;
    float* cbf = ws + WS_CB;
    float* sp  = ws + WS_SP;
    float* v   = ws + WS_V;
    float* pp  = ws + WS_PP;

    wb_precompute_kernel<<<dim3(256, 4), 256, 0, stream>>>(pcap_w, wBhi, wBlo);
    conv1_kernel<<<dim3(64, 16), 256, 0, stream>>>(x, conv_w, conv_b, h_hi, h_lo);
    conv2_mfma_kernel<<<dim3(32, 2, 8), 256, 0, stream>>>(h_hi, h_lo, wBhi, wBlo, pp);
    reduce_bias_squash_kernel<<<512, 256, 0, stream>>>(pp, pcap_b, u);
    transpose_u_kernel<<<128, 256, 0, stream>>>(u, ut);
    // routing iter 0 (c uniform = 1/100)
    r_weighted_mfma_kernel<1><<<dim3(100, 8), 256, 0, stream>>>(W, u, nullptr, sp);
    squash_v_kernel<<<400, 256, 0, stream>>>(sp, v);
    r_logits_mfma_kernel<0><<<dim3(100, 16), 256, 0, stream>>>(W, ut, v, bbf);
    // routing iter 1
    softmax_kernel<<<512, 256, 0, stream>>>(bbf, cbf);
    r_weighted_mfma_kernel<0><<<dim3(100, 8), 256, 0, stream>>>(W, u, cbf, sp);
    squash_v_kernel<<<400, 256, 0, stream>>>(sp, v);
    r_logits_mfma_kernel<1><<<dim3(100, 16), 256, 0, stream>>>(W, ut, v, bbf);
    // routing iter 2
    softmax_kernel<<<512, 256, 0, stream>>>(bbf, cbf);
    r_weighted_mfma_kernel<0><<<dim3(100, 8), 256, 0, stream>>>(W, u, cbf, sp);
    squash_v_kernel<<<400, 256, 0, stream>>>(sp, out);
}

// Round 20
// 780.038 us; speedup vs baseline: 1.2490x; 1.0580x over previous
//
#include <hip/hip_runtime.h>

#define NB 64
#define NO 100
#define NI 2048
#define ND 16
#define NK 8

// ws layout (float offsets)
#define WS_H    0            // h_hi/h_lo (conv phase); ut [16384][64] (routing phase)
#define WS_U    9437184      // u: 64*2048*8 = 1048576
#define WS_BB   10485760     // b logits: 13107200 (pp overlaps here pre-routing)
#define WS_CB   23592960     // c: 13107200 (w2 hi/lo overlap here pre-routing)
#define WS_SP   36700160     // s partials: 100*8*64*16 = 819200
#define WS_V    38338560     // v: 102400
#define WS_PP   WS_BB        // conv2 partials: 8*64*256*64 = 8388608 floats

typedef __attribute__((ext_vector_type(8))) short bf16x8;
typedef __attribute__((ext_vector_type(16))) float f32x16;
typedef __attribute__((ext_vector_type(4))) float f32x4;

__device__ inline unsigned short f2bf(float x) {   // RNE float->bf16
    union { float f; unsigned u; } v; v.f = x;
    unsigned r = (v.u + 0x7FFFu + ((v.u >> 16) & 1u)) >> 16;
    return (unsigned short)r;
}
__device__ inline float bf2f(unsigned short h) {
    union { unsigned u; float f; } v; v.u = ((unsigned)h) << 16;
    return v.f;
}

// ---------------- conv1: [64,3,32,32] -> relu -> h_hi/h_lo bf16 ----------------
__global__ __launch_bounds__(256) void conv1_kernel(const float* __restrict__ x,
        const float* __restrict__ w, const float* __restrict__ bias,
        unsigned short* __restrict__ h_hi, unsigned short* __restrict__ h_lo) {
    const int b = blockIdx.x;
    const int ocg = blockIdx.y;
    __shared__ float xl[3 * 32 * 32];
    __shared__ float wl[16 * 243];
    const int tid = threadIdx.x;
    for (int idx = tid; idx < 3072; idx += 256) xl[idx] = x[b * 3072 + idx];
    for (int idx = tid; idx < 16 * 243; idx += 256)
        wl[idx] = w[ocg * 16 * 243 + idx];
    __syncthreads();
    const int lane = tid & 63;
    const int wg = tid >> 6;
    float acc[4][9];
    #pragma unroll
    for (int jj = 0; jj < 4; ++jj) {
        float bv = bias[ocg * 16 + wg * 4 + jj];
        #pragma unroll
        for (int j = 0; j < 9; ++j) acc[jj][j] = bv;
    }
    int xbase[9];
    #pragma unroll
    for (int j = 0; j < 9; ++j) {
        int p = lane + 64 * j;
        xbase[j] = (p / 24) * 32 + (p % 24);
    }
    for (int ic = 0; ic < 3; ++ic)
        for (int ky = 0; ky < 9; ++ky) {
            #pragma unroll
            for (int kx = 0; kx < 9; ++kx) {
                float wv[4];
                #pragma unroll
                for (int jj = 0; jj < 4; ++jj)
                    wv[jj] = wl[(wg * 4 + jj) * 243 + ic * 81 + ky * 9 + kx];
                #pragma unroll
                for (int j = 0; j < 9; ++j) {
                    float xv = xl[ic * 1024 + xbase[j] + ky * 32 + kx];
                    #pragma unroll
                    for (int jj = 0; jj < 4; ++jj)
                        acc[jj][j] = fmaf(xv, wv[jj], acc[jj][j]);
                }
            }
        }
    #pragma unroll
    for (int jj = 0; jj < 4; ++jj) {
        int oc = ocg * 16 + wg * 4 + jj;
        #pragma unroll
        for (int j = 0; j < 9; ++j) {
            int p = lane + 64 * j;
            float v = fmaxf(acc[jj][j], 0.f);
            unsigned short hi = f2bf(v);
            unsigned short lo = f2bf(v - bf2f(hi));
            size_t o = (size_t)(b * 256 + oc) * 576 + p;
            h_hi[o] = hi;
            h_lo[o] = lo;
        }
    }
}

// ---- precompute w2_hi/lo[ic][oc][96] bf16, k' = ky*10+kx (kx=9, k'>=90 pad=0) ----
__global__ __launch_bounds__(256) void wb_precompute_kernel(const float* __restrict__ w,
        unsigned short* __restrict__ w2hi, unsigned short* __restrict__ w2lo) {
    const int ic = blockIdx.x;           // 0..255
    const int ocq = blockIdx.y;          // 0..3 (64 oc)
    __shared__ float tl[64][85];
    const int tid = threadIdx.x;
    for (int f = tid; f < 5184; f += 256) {
        int oc = f / 81, kk = f % 81;
        tl[oc][kk] = w[(size_t)(ocq * 64 + oc) * 20736 + ic * 81 + kk];
    }
    __syncthreads();
    for (int idx = tid; idx < 6144; idx += 256) {   // 64 oc x 96 k'
        int oc = idx / 96;
        int kp = idx % 96;
        int ky = kp / 10, kx = kp % 10;
        float val = (ky < 9 && kx < 9) ? tl[oc][ky * 9 + kx] : 0.f;
        unsigned short hi = f2bf(val);
        unsigned short lo = f2bf(val - bf2f(hi));
        size_t dst = ((size_t)ic * 256 + ocq * 64 + oc) * 96 + kp;
        w2hi[dst] = hi;
        w2lo[dst] = lo;
    }
}

// ---- conv2 via MFMA (split-bf16), v7: dense k-pack 96, per-ic B stage ----
// r19 counters: MFMA pipe ~103us of 248 vs 92us floor -> padding (144 vs 81
// real k) is the residual. v7: k' = ky*10+kx packed to 96 (6 chunks of 16);
// B = full 9-row x-window staged ONCE per ic (45 aligned dword writes, rows
// 100 shorts -> 2-way-free banks); A direct from global (wb2 rows 192B,
// fragments 16B-aligned, L2-resident). Barriers 576 -> 64; MFMAs 1.5x fewer.
// Pad slots have A=0; B pad k' 90..99 zeroed once (avoid 0*NaN).
__global__ __launch_bounds__(256) void conv2_mfma_kernel(
        const unsigned short* __restrict__ h_hi, const unsigned short* __restrict__ h_lo,
        const unsigned short* __restrict__ w2hi, const unsigned short* __restrict__ w2lo,
        float* __restrict__ pp) {
    const int bpair = blockIdx.x;        // 0..31
    const int ocb = blockIdx.y;          // 0..1  (128 oc)
    const int ks = blockIdx.z;           // 0..7  (32 ic)
    __shared__ __align__(16) unsigned short Bh[128 * 100];
    __shared__ __align__(16) unsigned short Bl[128 * 100];
    const int tid = threadIdx.x;
    const int lane = tid & 63;
    const int wid = tid >> 6;
    const int wr = wid >> 1, wc = wid & 1;
    const int l31 = lane & 31, kh = lane >> 5;
    const int slot = tid & 127;
    const int role = tid >> 7;
    const int oy = (slot >> 3) & 7;
    const int ox = slot & 7;
    const unsigned short* hsel = role ? h_lo : h_hi;
    const size_t hrow0 = ((size_t)(bpair * 2 + (slot >> 6)) * 256) * 576;
    const int ic0 = ks * 32;

    // zero B pad region k' 90..99 once (A is zero there; avoid 0*garbage-NaN)
    {
        unsigned int* Bz = (unsigned int*)((role ? Bl : Bh) + slot * 100 + 90);
        #pragma unroll
        for (int j = 0; j < 5; ++j) Bz[j] = 0u;
    }

    f32x16 acc[2][2];
    #pragma unroll
    for (int m = 0; m < 2; ++m)
        #pragma unroll
        for (int n = 0; n < 2; ++n)
            #pragma unroll
            for (int r = 0; r < 16; ++r) acc[m][n][r] = 0.f;

#define LDS64(arr, off, dst) { union { struct { uint2 a, b; } p; bf16x8 v; } u_;           \
    u_.p.a = *(const uint2*)((arr) + (off));                                               \
    u_.p.b = *(const uint2*)((arr) + (off) + 4);                                           \
    dst = u_.v; }

    #pragma unroll 1
    for (int ic_l = 0; ic_l < 32; ++ic_l) {
        const int ic = ic0 + ic_l;
        __syncthreads();                 // previous iteration's reads done
        // B stage: 9 rows x 5 dwords per slot, row ky -> short offset 10*ky
        {
            const size_t h_ic = hrow0 + (size_t)ic * 576;
            unsigned int* Brow = (unsigned int*)((role ? Bl : Bh) + slot * 100);
            #pragma unroll
            for (int ky = 0; ky < 9; ++ky) {
                const unsigned int* hp =
                    (const unsigned int*)(hsel + h_ic + (2 * oy + ky) * 24 + 2 * ox);
                unsigned int* dst = Brow + 5 * ky;
                dst[0] = hp[0]; dst[1] = hp[1]; dst[2] = hp[2];
                dst[3] = hp[3]; dst[4] = hp[4];
            }
        }
        __syncthreads();
        // 6 chunks of K=16; A direct from global
        const size_t wbase = ((size_t)ic * 256 + ocb * 128) * 96;
        #pragma unroll
        for (int c = 0; c < 6; ++c) {
            const size_t a0 = wbase + (size_t)(wr * 64 + l31) * 96 + 16 * c + 8 * kh;
            const size_t a1 = a0 + 32 * 96;
            bf16x8 ah0 = *(const bf16x8*)(w2hi + a0);
            bf16x8 ah1 = *(const bf16x8*)(w2hi + a1);
            bf16x8 al0 = *(const bf16x8*)(w2lo + a0);
            bf16x8 al1 = *(const bf16x8*)(w2lo + a1);
            bf16x8 bh0, bh1, bl0, bl1;
            const int b0 = (wc * 64 + l31) * 100 + 16 * c + 8 * kh;
            const int b1 = b0 + 32 * 100;
            LDS64(Bh, b0, bh0); LDS64(Bh, b1, bh1);
            LDS64(Bl, b0, bl0); LDS64(Bl, b1, bl1);
            acc[0][0] = __builtin_amdgcn_mfma_f32_32x32x16_bf16(ah0, bh0, acc[0][0], 0, 0, 0);
            acc[0][0] = __builtin_amdgcn_mfma_f32_32x32x16_bf16(ah0, bl0, acc[0][0], 0, 0, 0);
            acc[0][0] = __builtin_amdgcn_mfma_f32_32x32x16_bf16(al0, bh0, acc[0][0], 0, 0, 0);
            acc[0][1] = __builtin_amdgcn_mfma_f32_32x32x16_bf16(ah0, bh1, acc[0][1], 0, 0, 0);
            acc[0][1] = __builtin_amdgcn_mfma_f32_32x32x16_bf16(ah0, bl1, acc[0][1], 0, 0, 0);
            acc[0][1] = __builtin_amdgcn_mfma_f32_32x32x16_bf16(al0, bh1, acc[0][1], 0, 0, 0);
            acc[1][0] = __builtin_amdgcn_mfma_f32_32x32x16_bf16(ah1, bh0, acc[1][0], 0, 0, 0);
            acc[1][0] = __builtin_amdgcn_mfma_f32_32x32x16_bf16(ah1, bl0, acc[1][0], 0, 0, 0);
            acc[1][0] = __builtin_amdgcn_mfma_f32_32x32x16_bf16(al1, bh0, acc[1][0], 0, 0, 0);
            acc[1][1] = __builtin_amdgcn_mfma_f32_32x32x16_bf16(ah1, bh1, acc[1][1], 0, 0, 0);
            acc[1][1] = __builtin_amdgcn_mfma_f32_32x32x16_bf16(ah1, bl1, acc[1][1], 0, 0, 0);
            acc[1][1] = __builtin_amdgcn_mfma_f32_32x32x16_bf16(al1, bh1, acc[1][1], 0, 0, 0);
        }
    }
#undef LDS64
    #pragma unroll
    for (int m = 0; m < 2; ++m)
        #pragma unroll
        for (int n = 0; n < 2; ++n) {
            const int slotg = wc * 64 + n * 32 + l31;
            const int b = bpair * 2 + (slotg >> 6);
            const int pos = slotg & 63;
            #pragma unroll
            for (int r = 0; r < 16; ++r) {
                const int row = (r & 3) + 8 * (r >> 2) + 4 * kh;
                const int oc = ocb * 128 + wr * 64 + m * 32 + row;
                pp[(((size_t)ks * 64 + b) * 256 + oc) * 64 + pos] = acc[m][n][r];
            }
        }
}

// -------- reduce partials over ks, +bias, squash capsule rows of 8 -> u --------
__global__ __launch_bounds__(256) void reduce_bias_squash_kernel(
        const float* __restrict__ pp, const float* __restrict__ bias,
        float* __restrict__ u) {
    const int cap = blockIdx.x * 256 + threadIdx.x;
    const int b = cap >> 11;
    const int rem = cap & 2047;
    const int oc = rem >> 3;
    const int oy = rem & 7;
    float4 sa = {0.f, 0.f, 0.f, 0.f}, sb = {0.f, 0.f, 0.f, 0.f};
    #pragma unroll
    for (int ks = 0; ks < 8; ++ks) {
        const float4* p4 = (const float4*)&pp[(((size_t)ks * 64 + b) * 256 + oc) * 64 + oy * 8];
        float4 a = p4[0], c = p4[1];
        sa.x += a.x; sa.y += a.y; sa.z += a.z; sa.w += a.w;
        sb.x += c.x; sb.y += c.y; sb.z += c.z; sb.w += c.w;
    }
    const float bv = bias[oc];
    sa.x += bv; sa.y += bv; sa.z += bv; sa.w += bv;
    sb.x += bv; sb.y += bv; sb.z += bv; sb.w += bv;
    float s2 = sa.x * sa.x + sa.y * sa.y + sa.z * sa.z + sa.w * sa.w
             + sb.x * sb.x + sb.y * sb.y + sb.z * sb.z + sb.w * sb.w;
    float scale = (s2 / (1.f + s2)) / sqrtf(s2 + 1e-8f);
    sa.x *= scale; sa.y *= scale; sa.z *= scale; sa.w *= scale;
    sb.x *= scale; sb.y *= scale; sb.z *= scale; sb.w *= scale;
    float4* up = (float4*)&u[(size_t)cap * 8];
    up[0] = sa;
    up[1] = sb;
}

// -------- transpose u -> ut[(i*8+k)][b] (once per launch; u fixed in routing) ----
__global__ __launch_bounds__(256) void transpose_u_kernel(const float* __restrict__ u,
        float* __restrict__ ut) {
    const int blk = blockIdx.x;          // 128 blocks x 128 (i,k)-rows
    __shared__ float tl[64 * 132];
    const int tid = threadIdx.x;
    #pragma unroll
    for (int rep = 0; rep < 8; ++rep) {
        const int idx = tid + 256 * rep;        // 0..2047 float4s
        const int b = idx >> 5, q = idx & 31;
        float4 uv = *(const float4*)(u + (size_t)b * 16384 + blk * 128 + 4 * q);
        *(float4*)&tl[b * 132 + 4 * q] = uv;
    }
    __syncthreads();
    #pragma unroll
    for (int rep = 0; rep < 32; ++rep) {
        const int row = rep * 4 + (tid >> 6);
        const int b = tid & 63;
        ut[(size_t)(blk * 128 + row) * 64 + b] = tl[b * 132 + row];
    }
}

// ---- r_weighted via MFMA: per-o GEMM C[16d x 64b] = W[o]^T · (c ⊙ u) ----
template <int UNIFORM>
__global__ __launch_bounds__(256) void r_weighted_mfma_kernel(
        const float* __restrict__ W, const float* __restrict__ u,
        const float* __restrict__ cbuf, float* __restrict__ sp) {
    const int o = blockIdx.x;
    const int st = blockIdx.y;
    __shared__ __align__(16) unsigned short Ahi[16 * 72];
    __shared__ __align__(16) unsigned short Alo[16 * 72];
    __shared__ __align__(16) unsigned short Bhi[64 * 72];
    __shared__ __align__(16) unsigned short Blo[64 * 72];
    const int tid = threadIdx.x;
    const int lane = tid & 63;
    const int w = tid >> 6;
    const int l15 = lane & 15;
    const int hi = lane >> 4;
    const int sb = tid >> 2;
    const int si = tid & 3;
    f32x4 acc = {0.f, 0.f, 0.f, 0.f};
    const float* Wo = W + (size_t)o * 262144;
    const int i_base = st * 256;
    #pragma unroll 1
    for (int iter = 0; iter < 32; ++iter) {
        const int i0 = i_base + iter * 8;
        __syncthreads();
        {
            float4 wv = *(const float4*)(Wo + (size_t)i0 * 128 + 4 * tid);
            const int i_l = tid >> 5;
            const int d = (tid >> 1) & 15;
            const int k0 = (tid & 1) * 4;
            unsigned short* dh = Ahi + d * 72 + i_l * 8 + k0;
            unsigned short* dl = Alo + d * 72 + i_l * 8 + k0;
            float vv[4] = {wv.x, wv.y, wv.z, wv.w};
            unsigned int h01, h23, l01, l23;
            unsigned short h, l;
            h = f2bf(vv[0]); l = f2bf(vv[0] - bf2f(h)); h01 = h; l01 = l;
            h = f2bf(vv[1]); l = f2bf(vv[1] - bf2f(h)); h01 |= (unsigned)h << 16; l01 |= (unsigned)l << 16;
            h = f2bf(vv[2]); l = f2bf(vv[2] - bf2f(h)); h23 = h; l23 = l;
            h = f2bf(vv[3]); l = f2bf(vv[3] - bf2f(h)); h23 |= (unsigned)h << 16; l23 |= (unsigned)l << 16;
            *(unsigned int*)dh = h01; *(unsigned int*)(dh + 2) = h23;
            *(unsigned int*)dl = l01; *(unsigned int*)(dl + 2) = l23;
        }
        #pragma unroll
        for (int half = 0; half < 2; ++half) {
            const int i_l = si + 4 * half;
            const float* up = u + (size_t)sb * 16384 + (size_t)(i0 + i_l) * 8;
            float4 u0 = *(const float4*)up;
            float4 u1 = *(const float4*)(up + 4);
            float cv = UNIFORM ? 0.01f
                               : cbuf[(size_t)sb * (NO * NI) + o * NI + i0 + i_l];
            float q[8] = {u0.x * cv, u0.y * cv, u0.z * cv, u0.w * cv,
                          u1.x * cv, u1.y * cv, u1.z * cv, u1.w * cv};
            uint4 ph, pl;
            unsigned short h0, h1, l0, l1;
            h0 = f2bf(q[0]); l0 = f2bf(q[0] - bf2f(h0));
            h1 = f2bf(q[1]); l1 = f2bf(q[1] - bf2f(h1));
            ph.x = h0 | ((unsigned)h1 << 16); pl.x = l0 | ((unsigned)l1 << 16);
            h0 = f2bf(q[2]); l0 = f2bf(q[2] - bf2f(h0));
            h1 = f2bf(q[3]); l1 = f2bf(q[3] - bf2f(h1));
            ph.y = h0 | ((unsigned)h1 << 16); pl.y = l0 | ((unsigned)l1 << 16);
            h0 = f2bf(q[4]); l0 = f2bf(q[4] - bf2f(h0));
            h1 = f2bf(q[5]); l1 = f2bf(q[5] - bf2f(h1));
            ph.z = h0 | ((unsigned)h1 << 16); pl.z = l0 | ((unsigned)l1 << 16);
            h0 = f2bf(q[6]); l0 = f2bf(q[6] - bf2f(h0));
            h1 = f2bf(q[7]); l1 = f2bf(q[7] - bf2f(h1));
            ph.w = h0 | ((unsigned)h1 << 16); pl.w = l0 | ((unsigned)l1 << 16);
            *(uint4*)(Bhi + sb * 72 + i_l * 8) = ph;
            *(uint4*)(Blo + sb * 72 + i_l * 8) = pl;
        }
        __syncthreads();
        #pragma unroll
        for (int ch = 0; ch < 2; ++ch) {
            bf16x8 ah = *(const bf16x8*)(Ahi + l15 * 72 + ch * 32 + hi * 8);
            bf16x8 al = *(const bf16x8*)(Alo + l15 * 72 + ch * 32 + hi * 8);
            bf16x8 bh = *(const bf16x8*)(Bhi + (w * 16 + l15) * 72 + ch * 32 + hi * 8);
            bf16x8 bl = *(const bf16x8*)(Blo + (w * 16 + l15) * 72 + ch * 32 + hi * 8);
            acc = __builtin_amdgcn_mfma_f32_16x16x32_bf16(ah, bh, acc, 0, 0, 0);
            acc = __builtin_amdgcn_mfma_f32_16x16x32_bf16(ah, bl, acc, 0, 0, 0);
            acc = __builtin_amdgcn_mfma_f32_16x16x32_bf16(al, bh, acc, 0, 0, 0);
        }
    }
    const int bg = w * 16 + l15;
    float4 st4;
    st4.x = acc[0]; st4.y = acc[1]; st4.z = acc[2]; st4.w = acc[3];
    *(float4*)&sp[(((size_t)o * 8 + st) * 64 + bg) * 16 + hi * 4] = st4;
}

// -------- reduce partials over st (8), squash over d, write v/out --------
__global__ __launch_bounds__(256) void squash_v_kernel(const float* __restrict__ sp,
        float* __restrict__ dest) {
    const int t = blockIdx.x * 256 + threadIdx.x;
    const int d = t & 15;
    const int cap = t >> 4;
    const int o = cap >> 6;
    const int bb = cap & 63;
    float s = 0.f;
    #pragma unroll
    for (int st = 0; st < 8; ++st)
        s += sp[(((size_t)o * 8 + st) * 64 + bb) * 16 + d];
    float s2 = s * s;
    #pragma unroll
    for (int off = 1; off < 16; off <<= 1)
        s2 += __shfl_xor(s2, off, 16);
    float scale = (s2 / (1.f + s2)) / sqrtf(s2 + 1e-8f);
    dest[(bb * NO + o) * ND + d] = s * scale;
}

// ---- r_logits via MFMA: per-o GEMM G[(i,k) x b] = [Wh|Wl] · [v...]; then
// in-register k-reduce with ut.
template <int ADD>
__global__ __launch_bounds__(256) void r_logits_mfma_kernel(
        const float* __restrict__ W, const float* __restrict__ ut,
        const float* __restrict__ v, float* __restrict__ bbuf) {
    const int o = blockIdx.x;
    const int st = blockIdx.y;               // 128 i per block
    __shared__ __align__(16) unsigned short Aext[128 * 40];
    __shared__ __align__(16) unsigned short B1[64 * 40];
    __shared__ __align__(16) unsigned short B2[64 * 40];
    __shared__ float ul[128 * 66];
    const int tid = threadIdx.x;
    const int lane = tid & 63;
    const int w = tid >> 6;
    const int l15 = lane & 15;
    const int hi = lane >> 4;
    const float* Wo = W + (size_t)o * 262144;
    {
        const int b = tid >> 2;
        const int dq = (tid & 3) * 4;
        float4 vv = *(const float4*)&v[((size_t)b * NO + o) * ND + dq];
        float q[4] = {vv.x, vv.y, vv.z, vv.w};
        #pragma unroll
        for (int c = 0; c < 4; ++c) {
            unsigned short h = f2bf(q[c]);
            unsigned short l = f2bf(q[c] - bf2f(h));
            B1[b * 40 + dq + c] = h;
            B1[b * 40 + 16 + dq + c] = h;
            B2[b * 40 + dq + c] = l;
            B2[b * 40 + 16 + dq + c] = 0;
        }
    }
    __syncthreads();
    #pragma unroll 1
    for (int iter = 0; iter < 8; ++iter) {
        __syncthreads();
        #pragma unroll
        for (int rep = 0; rep < 2; ++rep) {
            const int slot = rep * 256 + tid;
            const int i_l = slot >> 5;
            const int dgrp = (slot >> 3) & 3;
            const int k = slot & 7;
            const float* src = Wo + (size_t)(st * 128 + iter * 16 + i_l) * 128
                             + dgrp * 32 + k;
            float v0 = src[0], v1 = src[8], v2 = src[16], v3 = src[24];
            unsigned short h0 = f2bf(v0), l0 = f2bf(v0 - bf2f(h0));
            unsigned short h1 = f2bf(v1), l1 = f2bf(v1 - bf2f(h1));
            unsigned short h2 = f2bf(v2), l2 = f2bf(v2 - bf2f(h2));
            unsigned short h3 = f2bf(v3), l3 = f2bf(v3 - bf2f(h3));
            uint2 ph; ph.x = h0 | ((unsigned)h1 << 16); ph.y = h2 | ((unsigned)h3 << 16);
            uint2 pl; pl.x = l0 | ((unsigned)l1 << 16); pl.y = l2 | ((unsigned)l3 << 16);
            unsigned short* dst = Aext + (i_l * 8 + k) * 40 + dgrp * 4;
            *(uint2*)dst = ph;
            *(uint2*)(dst + 16) = pl;
        }
        const int base_row = (st * 128 + iter * 16) * 8;
        #pragma unroll
        for (int rep = 0; rep < 8; ++rep) {
            const int idx = tid + 256 * rep;
            const int row = idx >> 4, bq = idx & 15;
            float4 uv = *(const float4*)(ut + (size_t)(base_row + row) * 64 + 4 * bq);
            *(float4*)&ul[row * 66 + 4 * bq] = uv;
        }
        __syncthreads();
        f32x4 acc[8];
        bf16x8 bf1 = *(const bf16x8*)&B1[(w * 16 + l15) * 40 + hi * 8];
        bf16x8 bf2 = *(const bf16x8*)&B2[(w * 16 + l15) * 40 + hi * 8];
        #pragma unroll
        for (int mt = 0; mt < 8; ++mt) {
            f32x4 z = {0.f, 0.f, 0.f, 0.f};
            bf16x8 af = *(const bf16x8*)&Aext[(mt * 16 + l15) * 40 + hi * 8];
            z = __builtin_amdgcn_mfma_f32_16x16x32_bf16(af, bf1, z, 0, 0, 0);
            z = __builtin_amdgcn_mfma_f32_16x16x32_bf16(af, bf2, z, 0, 0, 0);
            acc[mt] = z;
        }
        #pragma unroll
        for (int mt = 0; mt < 8; ++mt) {
            float partial = 0.f;
            #pragma unroll
            for (int r = 0; r < 4; ++r) {
                const int grow = mt * 16 + hi * 4 + r;
                partial = fmaf(acc[mt][r], ul[grow * 66 + w * 16 + l15], partial);
            }
            float sum = partial + __shfl_xor(partial, 16);
            if ((hi & 1) == 0) {
                const int i_glob = st * 128 + iter * 16 + mt * 2 + (hi >> 1);
                const int bg = w * 16 + l15;
                const size_t addr = (size_t)bg * (NO * NI) + (size_t)o * NI + i_glob;
                bbuf[addr] = (ADD ? bbuf[addr] : 0.f) + sum;
            }
        }
    }
}

// -------- softmax over o (axis=1) of b -> c --------
__global__ __launch_bounds__(256) void softmax_kernel(const float* __restrict__ bbuf,
        float* __restrict__ cbuf) {
    const int bb = blockIdx.x >> 3;
    const int i = (blockIdx.x & 7) * 256 + threadIdx.x;
    const float* col = bbuf + bb * (NO * NI) + i;
    float m = -1e30f;
    for (int o = 0; o < NO; ++o) m = fmaxf(m, col[o * NI]);
    float s = 0.f;
    for (int o = 0; o < NO; ++o) s += __expf(col[o * NI] - m);
    const float inv = 1.f / s;
    float* outp = cbuf + bb * (NO * NI) + i;
    for (int o = 0; o < NO; ++o) outp[o * NI] = __expf(col[o * NI] - m) * inv;
}

extern "C" void kernel_launch(void* const* d_in, const int* in_sizes, int n_in,
                              void* d_out, int out_size, void* d_ws, size_t ws_size,
                              hipStream_t stream) {
    (void)in_sizes; (void)n_in; (void)out_size; (void)ws_size;
    const float* x      = (const float*)d_in[0];
    const float* conv_w = (const float*)d_in[1];
    const float* conv_b = (const float*)d_in[2];
    const float* pcap_w = (const float*)d_in[3];
    const float* pcap_b = (const float*)d_in[4];
    const float* W      = (const float*)d_in[5];
    float* out = (float*)d_out;
    float* ws  = (float*)d_ws;
    unsigned short* h_hi = (unsigned short*)(ws + WS_H);
    unsigned short* h_lo = h_hi + 9437184;
    unsigned short* w2hi = (unsigned short*)(ws + WS_CB);   // 256*256*96 = 6291456
    unsigned short* w2lo = w2hi + 6291456;
    float* ut  = ws + WS_H;    // overlaps h (dead after conv2)
    float* u   = ws + WS_U;
    float* bbf = ws + WS_BB;
    float* cbf = ws + WS_CB;
    float* sp  = ws + WS_SP;
    float* v   = ws + WS_V;
    float* pp  = ws + WS_PP;

    wb_precompute_kernel<<<dim3(256, 4), 256, 0, stream>>>(pcap_w, w2hi, w2lo);
    conv1_kernel<<<dim3(64, 16), 256, 0, stream>>>(x, conv_w, conv_b, h_hi, h_lo);
    conv2_mfma_kernel<<<dim3(32, 2, 8), 256, 0, stream>>>(h_hi, h_lo, w2hi, w2lo, pp);
    reduce_bias_squash_kernel<<<512, 256, 0, stream>>>(pp, pcap_b, u);
    transpose_u_kernel<<<128, 256, 0, stream>>>(u, ut);
    // routing iter 0 (c uniform = 1/100)
    r_weighted_mfma_kernel<1><<<dim3(100, 8), 256, 0, stream>>>(W, u, nullptr, sp);
    squash_v_kernel<<<400, 256, 0, stream>>>(sp, v);
    r_logits_mfma_kernel<0><<<dim3(100, 16), 256, 0, stream>>>(W, ut, v, bbf);
    // routing iter 1
    softmax_kernel<<<512, 256, 0, stream>>>(bbf, cbf);
    r_weighted_mfma_kernel<0><<<dim3(100, 8), 256, 0, stream>>>(W, u, cbf, sp);
    squash_v_kernel<<<400, 256, 0, stream>>>(sp, v);
    r_logits_mfma_kernel<1><<<dim3(100, 16), 256, 0, stream>>>(W, ut, v, bbf);
    // routing iter 2
    softmax_kernel<<<512, 256, 0, stream>>>(bbf, cbf);
    r_weighted_mfma_kernel<0><<<dim3(100, 8), 256, 0, stream>>>(W, u, cbf, sp);
    squash_v_kernel<<<400, 256, 0, stream>>>(sp, out);
}

// Round 21
// 741.525 us; speedup vs baseline: 1.3139x; 1.0519x over previous
//
#include <hip/hip_runtime.h>

#define NB 64
#define NO 100
#define NI 2048
#define ND 16
#define NK 8

// ws layout (float offsets)
#define WS_H    0            // h_hi/h_lo (conv phase); ut [16384][64] (routing phase)
#define WS_U    9437184      // u: 64*2048*8 = 1048576
#define WS_BB   10485760     // b logits: 13107200 (pp overlaps here pre-routing)
#define WS_CB   23592960     // c: 13107200 (w2 hi/lo overlap here pre-routing)
#define WS_SP   36700160     // s partials: 100*8*64*16 = 819200
#define WS_V    38338560     // v: 102400
#define WS_PP   WS_BB        // conv2 partials: 8*64*256*64 = 8388608 floats

typedef __attribute__((ext_vector_type(8))) short bf16x8;
typedef __attribute__((ext_vector_type(16))) float f32x16;
typedef __attribute__((ext_vector_type(4))) float f32x4;

__device__ inline unsigned short f2bf(float x) {   // RNE float->bf16
    union { float f; unsigned u; } v; v.f = x;
    unsigned r = (v.u + 0x7FFFu + ((v.u >> 16) & 1u)) >> 16;
    return (unsigned short)r;
}
__device__ inline float bf2f(unsigned short h) {
    union { unsigned u; float f; } v; v.u = ((unsigned)h) << 16;
    return v.f;
}

// ---------------- conv1: [64,3,32,32] -> relu -> h_hi/h_lo bf16 ----------------
__global__ __launch_bounds__(256) void conv1_kernel(const float* __restrict__ x,
        const float* __restrict__ w, const float* __restrict__ bias,
        unsigned short* __restrict__ h_hi, unsigned short* __restrict__ h_lo) {
    const int b = blockIdx.x;
    const int ocg = blockIdx.y;
    __shared__ float xl[3 * 32 * 32];
    __shared__ float wl[16 * 243];
    const int tid = threadIdx.x;
    for (int idx = tid; idx < 3072; idx += 256) xl[idx] = x[b * 3072 + idx];
    for (int idx = tid; idx < 16 * 243; idx += 256)
        wl[idx] = w[ocg * 16 * 243 + idx];
    __syncthreads();
    const int lane = tid & 63;
    const int wg = tid >> 6;
    float acc[4][9];
    #pragma unroll
    for (int jj = 0; jj < 4; ++jj) {
        float bv = bias[ocg * 16 + wg * 4 + jj];
        #pragma unroll
        for (int j = 0; j < 9; ++j) acc[jj][j] = bv;
    }
    int xbase[9];
    #pragma unroll
    for (int j = 0; j < 9; ++j) {
        int p = lane + 64 * j;
        xbase[j] = (p / 24) * 32 + (p % 24);
    }
    for (int ic = 0; ic < 3; ++ic)
        for (int ky = 0; ky < 9; ++ky) {
            #pragma unroll
            for (int kx = 0; kx < 9; ++kx) {
                float wv[4];
                #pragma unroll
                for (int jj = 0; jj < 4; ++jj)
                    wv[jj] = wl[(wg * 4 + jj) * 243 + ic * 81 + ky * 9 + kx];
                #pragma unroll
                for (int j = 0; j < 9; ++j) {
                    float xv = xl[ic * 1024 + xbase[j] + ky * 32 + kx];
                    #pragma unroll
                    for (int jj = 0; jj < 4; ++jj)
                        acc[jj][j] = fmaf(xv, wv[jj], acc[jj][j]);
                }
            }
        }
    #pragma unroll
    for (int jj = 0; jj < 4; ++jj) {
        int oc = ocg * 16 + wg * 4 + jj;
        #pragma unroll
        for (int j = 0; j < 9; ++j) {
            int p = lane + 64 * j;
            float v = fmaxf(acc[jj][j], 0.f);
            unsigned short hi = f2bf(v);
            unsigned short lo = f2bf(v - bf2f(hi));
            size_t o = (size_t)(b * 256 + oc) * 576 + p;
            h_hi[o] = hi;
            h_lo[o] = lo;
        }
    }
}

// ---- precompute w2_hi/lo[ic][oc][96] bf16, k' = ky*10+kx (kx=9, k'>=90 pad=0) ----
__global__ __launch_bounds__(256) void wb_precompute_kernel(const float* __restrict__ w,
        unsigned short* __restrict__ w2hi, unsigned short* __restrict__ w2lo) {
    const int ic = blockIdx.x;           // 0..255
    const int ocq = blockIdx.y;          // 0..3 (64 oc)
    __shared__ float tl[64][85];
    const int tid = threadIdx.x;
    for (int f = tid; f < 5184; f += 256) {
        int oc = f / 81, kk = f % 81;
        tl[oc][kk] = w[(size_t)(ocq * 64 + oc) * 20736 + ic * 81 + kk];
    }
    __syncthreads();
    for (int idx = tid; idx < 6144; idx += 256) {   // 64 oc x 96 k'
        int oc = idx / 96;
        int kp = idx % 96;
        int ky = kp / 10, kx = kp % 10;
        float val = (ky < 9 && kx < 9) ? tl[oc][ky * 9 + kx] : 0.f;
        unsigned short hi = f2bf(val);
        unsigned short lo = f2bf(val - bf2f(hi));
        size_t dst = ((size_t)ic * 256 + ocq * 64 + oc) * 96 + kp;
        w2hi[dst] = hi;
        w2lo[dst] = lo;
    }
}

// ---- conv2 via MFMA (split-bf16), v7: dense k-pack 96, per-ic B stage ----
// At MFMA floor (192us, pipe-busy ~65us vs 61us dense floor). FROZEN.
__global__ __launch_bounds__(256) void conv2_mfma_kernel(
        const unsigned short* __restrict__ h_hi, const unsigned short* __restrict__ h_lo,
        const unsigned short* __restrict__ w2hi, const unsigned short* __restrict__ w2lo,
        float* __restrict__ pp) {
    const int bpair = blockIdx.x;        // 0..31
    const int ocb = blockIdx.y;          // 0..1  (128 oc)
    const int ks = blockIdx.z;           // 0..7  (32 ic)
    __shared__ __align__(16) unsigned short Bh[128 * 100];
    __shared__ __align__(16) unsigned short Bl[128 * 100];
    const int tid = threadIdx.x;
    const int lane = tid & 63;
    const int wid = tid >> 6;
    const int wr = wid >> 1, wc = wid & 1;
    const int l31 = lane & 31, kh = lane >> 5;
    const int slot = tid & 127;
    const int role = tid >> 7;
    const int oy = (slot >> 3) & 7;
    const int ox = slot & 7;
    const unsigned short* hsel = role ? h_lo : h_hi;
    const size_t hrow0 = ((size_t)(bpair * 2 + (slot >> 6)) * 256) * 576;
    const int ic0 = ks * 32;

    {
        unsigned int* Bz = (unsigned int*)((role ? Bl : Bh) + slot * 100 + 90);
        #pragma unroll
        for (int j = 0; j < 5; ++j) Bz[j] = 0u;
    }

    f32x16 acc[2][2];
    #pragma unroll
    for (int m = 0; m < 2; ++m)
        #pragma unroll
        for (int n = 0; n < 2; ++n)
            #pragma unroll
            for (int r = 0; r < 16; ++r) acc[m][n][r] = 0.f;

#define LDS64(arr, off, dst) { union { struct { uint2 a, b; } p; bf16x8 v; } u_;           \
    u_.p.a = *(const uint2*)((arr) + (off));                                               \
    u_.p.b = *(const uint2*)((arr) + (off) + 4);                                           \
    dst = u_.v; }

    #pragma unroll 1
    for (int ic_l = 0; ic_l < 32; ++ic_l) {
        const int ic = ic0 + ic_l;
        __syncthreads();
        {
            const size_t h_ic = hrow0 + (size_t)ic * 576;
            unsigned int* Brow = (unsigned int*)((role ? Bl : Bh) + slot * 100);
            #pragma unroll
            for (int ky = 0; ky < 9; ++ky) {
                const unsigned int* hp =
                    (const unsigned int*)(hsel + h_ic + (2 * oy + ky) * 24 + 2 * ox);
                unsigned int* dst = Brow + 5 * ky;
                dst[0] = hp[0]; dst[1] = hp[1]; dst[2] = hp[2];
                dst[3] = hp[3]; dst[4] = hp[4];
            }
        }
        __syncthreads();
        const size_t wbase = ((size_t)ic * 256 + ocb * 128) * 96;
        #pragma unroll
        for (int c = 0; c < 6; ++c) {
            const size_t a0 = wbase + (size_t)(wr * 64 + l31) * 96 + 16 * c + 8 * kh;
            const size_t a1 = a0 + 32 * 96;
            bf16x8 ah0 = *(const bf16x8*)(w2hi + a0);
            bf16x8 ah1 = *(const bf16x8*)(w2hi + a1);
            bf16x8 al0 = *(const bf16x8*)(w2lo + a0);
            bf16x8 al1 = *(const bf16x8*)(w2lo + a1);
            bf16x8 bh0, bh1, bl0, bl1;
            const int b0 = (wc * 64 + l31) * 100 + 16 * c + 8 * kh;
            const int b1 = b0 + 32 * 100;
            LDS64(Bh, b0, bh0); LDS64(Bh, b1, bh1);
            LDS64(Bl, b0, bl0); LDS64(Bl, b1, bl1);
            acc[0][0] = __builtin_amdgcn_mfma_f32_32x32x16_bf16(ah0, bh0, acc[0][0], 0, 0, 0);
            acc[0][0] = __builtin_amdgcn_mfma_f32_32x32x16_bf16(ah0, bl0, acc[0][0], 0, 0, 0);
            acc[0][0] = __builtin_amdgcn_mfma_f32_32x32x16_bf16(al0, bh0, acc[0][0], 0, 0, 0);
            acc[0][1] = __builtin_amdgcn_mfma_f32_32x32x16_bf16(ah0, bh1, acc[0][1], 0, 0, 0);
            acc[0][1] = __builtin_amdgcn_mfma_f32_32x32x16_bf16(ah0, bl1, acc[0][1], 0, 0, 0);
            acc[0][1] = __builtin_amdgcn_mfma_f32_32x32x16_bf16(al0, bh1, acc[0][1], 0, 0, 0);
            acc[1][0] = __builtin_amdgcn_mfma_f32_32x32x16_bf16(ah1, bh0, acc[1][0], 0, 0, 0);
            acc[1][0] = __builtin_amdgcn_mfma_f32_32x32x16_bf16(ah1, bl0, acc[1][0], 0, 0, 0);
            acc[1][0] = __builtin_amdgcn_mfma_f32_32x32x16_bf16(al1, bh0, acc[1][0], 0, 0, 0);
            acc[1][1] = __builtin_amdgcn_mfma_f32_32x32x16_bf16(ah1, bh1, acc[1][1], 0, 0, 0);
            acc[1][1] = __builtin_amdgcn_mfma_f32_32x32x16_bf16(ah1, bl1, acc[1][1], 0, 0, 0);
            acc[1][1] = __builtin_amdgcn_mfma_f32_32x32x16_bf16(al1, bh1, acc[1][1], 0, 0, 0);
        }
    }
#undef LDS64
    #pragma unroll
    for (int m = 0; m < 2; ++m)
        #pragma unroll
        for (int n = 0; n < 2; ++n) {
            const int slotg = wc * 64 + n * 32 + l31;
            const int b = bpair * 2 + (slotg >> 6);
            const int pos = slotg & 63;
            #pragma unroll
            for (int r = 0; r < 16; ++r) {
                const int row = (r & 3) + 8 * (r >> 2) + 4 * kh;
                const int oc = ocb * 128 + wr * 64 + m * 32 + row;
                pp[(((size_t)ks * 64 + b) * 256 + oc) * 64 + pos] = acc[m][n][r];
            }
        }
}

// -------- reduce partials over ks, +bias, squash capsule rows of 8 -> u --------
__global__ __launch_bounds__(256) void reduce_bias_squash_kernel(
        const float* __restrict__ pp, const float* __restrict__ bias,
        float* __restrict__ u) {
    const int cap = blockIdx.x * 256 + threadIdx.x;
    const int b = cap >> 11;
    const int rem = cap & 2047;
    const int oc = rem >> 3;
    const int oy = rem & 7;
    float4 sa = {0.f, 0.f, 0.f, 0.f}, sb = {0.f, 0.f, 0.f, 0.f};
    #pragma unroll
    for (int ks = 0; ks < 8; ++ks) {
        const float4* p4 = (const float4*)&pp[(((size_t)ks * 64 + b) * 256 + oc) * 64 + oy * 8];
        float4 a = p4[0], c = p4[1];
        sa.x += a.x; sa.y += a.y; sa.z += a.z; sa.w += a.w;
        sb.x += c.x; sb.y += c.y; sb.z += c.z; sb.w += c.w;
    }
    const float bv = bias[oc];
    sa.x += bv; sa.y += bv; sa.z += bv; sa.w += bv;
    sb.x += bv; sb.y += bv; sb.z += bv; sb.w += bv;
    float s2 = sa.x * sa.x + sa.y * sa.y + sa.z * sa.z + sa.w * sa.w
             + sb.x * sb.x + sb.y * sb.y + sb.z * sb.z + sb.w * sb.w;
    float scale = (s2 / (1.f + s2)) / sqrtf(s2 + 1e-8f);
    sa.x *= scale; sa.y *= scale; sa.z *= scale; sa.w *= scale;
    sb.x *= scale; sb.y *= scale; sb.z *= scale; sb.w *= scale;
    float4* up = (float4*)&u[(size_t)cap * 8];
    up[0] = sa;
    up[1] = sb;
}

// -------- transpose u -> ut[(i*8+k)][b] (once per launch; u fixed in routing) ----
__global__ __launch_bounds__(256) void transpose_u_kernel(const float* __restrict__ u,
        float* __restrict__ ut) {
    const int blk = blockIdx.x;          // 128 blocks x 128 (i,k)-rows
    __shared__ float tl[64 * 132];
    const int tid = threadIdx.x;
    #pragma unroll
    for (int rep = 0; rep < 8; ++rep) {
        const int idx = tid + 256 * rep;        // 0..2047 float4s
        const int b = idx >> 5, q = idx & 31;
        float4 uv = *(const float4*)(u + (size_t)b * 16384 + blk * 128 + 4 * q);
        *(float4*)&tl[b * 132 + 4 * q] = uv;
    }
    __syncthreads();
    #pragma unroll
    for (int rep = 0; rep < 32; ++rep) {
        const int row = rep * 4 + (tid >> 6);
        const int b = tid & 63;
        ut[(size_t)(blk * 128 + row) * 64 + b] = tl[b * 132 + row];
    }
}

// ---- r_weighted via MFMA: per-o GEMM C[16d x 64b] = W[o]^T · (c ⊙ u) ----
template <int UNIFORM>
__global__ __launch_bounds__(256) void r_weighted_mfma_kernel(
        const float* __restrict__ W, const float* __restrict__ u,
        const float* __restrict__ cbuf, float* __restrict__ sp) {
    const int o = blockIdx.x;
    const int st = blockIdx.y;
    __shared__ __align__(16) unsigned short Ahi[16 * 72];
    __shared__ __align__(16) unsigned short Alo[16 * 72];
    __shared__ __align__(16) unsigned short Bhi[64 * 72];
    __shared__ __align__(16) unsigned short Blo[64 * 72];
    const int tid = threadIdx.x;
    const int lane = tid & 63;
    const int w = tid >> 6;
    const int l15 = lane & 15;
    const int hi = lane >> 4;
    const int sb = tid >> 2;
    const int si = tid & 3;
    f32x4 acc = {0.f, 0.f, 0.f, 0.f};
    const float* Wo = W + (size_t)o * 262144;
    const int i_base = st * 256;
    #pragma unroll 1
    for (int iter = 0; iter < 32; ++iter) {
        const int i0 = i_base + iter * 8;
        __syncthreads();
        {
            float4 wv = *(const float4*)(Wo + (size_t)i0 * 128 + 4 * tid);
            const int i_l = tid >> 5;
            const int d = (tid >> 1) & 15;
            const int k0 = (tid & 1) * 4;
            unsigned short* dh = Ahi + d * 72 + i_l * 8 + k0;
            unsigned short* dl = Alo + d * 72 + i_l * 8 + k0;
            float vv[4] = {wv.x, wv.y, wv.z, wv.w};
            unsigned int h01, h23, l01, l23;
            unsigned short h, l;
            h = f2bf(vv[0]); l = f2bf(vv[0] - bf2f(h)); h01 = h; l01 = l;
            h = f2bf(vv[1]); l = f2bf(vv[1] - bf2f(h)); h01 |= (unsigned)h << 16; l01 |= (unsigned)l << 16;
            h = f2bf(vv[2]); l = f2bf(vv[2] - bf2f(h)); h23 = h; l23 = l;
            h = f2bf(vv[3]); l = f2bf(vv[3] - bf2f(h)); h23 |= (unsigned)h << 16; l23 |= (unsigned)l << 16;
            *(unsigned int*)dh = h01; *(unsigned int*)(dh + 2) = h23;
            *(unsigned int*)dl = l01; *(unsigned int*)(dl + 2) = l23;
        }
        #pragma unroll
        for (int half = 0; half < 2; ++half) {
            const int i_l = si + 4 * half;
            const float* up = u + (size_t)sb * 16384 + (size_t)(i0 + i_l) * 8;
            float4 u0 = *(const float4*)up;
            float4 u1 = *(const float4*)(up + 4);
            float cv = UNIFORM ? 0.01f
                               : cbuf[(size_t)sb * (NO * NI) + o * NI + i0 + i_l];
            float q[8] = {u0.x * cv, u0.y * cv, u0.z * cv, u0.w * cv,
                          u1.x * cv, u1.y * cv, u1.z * cv, u1.w * cv};
            uint4 ph, pl;
            unsigned short h0, h1, l0, l1;
            h0 = f2bf(q[0]); l0 = f2bf(q[0] - bf2f(h0));
            h1 = f2bf(q[1]); l1 = f2bf(q[1] - bf2f(h1));
            ph.x = h0 | ((unsigned)h1 << 16); pl.x = l0 | ((unsigned)l1 << 16);
            h0 = f2bf(q[2]); l0 = f2bf(q[2] - bf2f(h0));
            h1 = f2bf(q[3]); l1 = f2bf(q[3] - bf2f(h1));
            ph.y = h0 | ((unsigned)h1 << 16); pl.y = l0 | ((unsigned)l1 << 16);
            h0 = f2bf(q[4]); l0 = f2bf(q[4] - bf2f(h0));
            h1 = f2bf(q[5]); l1 = f2bf(q[5] - bf2f(h1));
            ph.z = h0 | ((unsigned)h1 << 16); pl.z = l0 | ((unsigned)l1 << 16);
            h0 = f2bf(q[6]); l0 = f2bf(q[6] - bf2f(h0));
            h1 = f2bf(q[7]); l1 = f2bf(q[7] - bf2f(h1));
            ph.w = h0 | ((unsigned)h1 << 16); pl.w = l0 | ((unsigned)l1 << 16);
            *(uint4*)(Bhi + sb * 72 + i_l * 8) = ph;
            *(uint4*)(Blo + sb * 72 + i_l * 8) = pl;
        }
        __syncthreads();
        #pragma unroll
        for (int ch = 0; ch < 2; ++ch) {
            bf16x8 ah = *(const bf16x8*)(Ahi + l15 * 72 + ch * 32 + hi * 8);
            bf16x8 al = *(const bf16x8*)(Alo + l15 * 72 + ch * 32 + hi * 8);
            bf16x8 bh = *(const bf16x8*)(Bhi + (w * 16 + l15) * 72 + ch * 32 + hi * 8);
            bf16x8 bl = *(const bf16x8*)(Blo + (w * 16 + l15) * 72 + ch * 32 + hi * 8);
            acc = __builtin_amdgcn_mfma_f32_16x16x32_bf16(ah, bh, acc, 0, 0, 0);
            acc = __builtin_amdgcn_mfma_f32_16x16x32_bf16(ah, bl, acc, 0, 0, 0);
            acc = __builtin_amdgcn_mfma_f32_16x16x32_bf16(al, bh, acc, 0, 0, 0);
        }
    }
    const int bg = w * 16 + l15;
    float4 st4;
    st4.x = acc[0]; st4.y = acc[1]; st4.z = acc[2]; st4.w = acc[3];
    *(float4*)&sp[(((size_t)o * 8 + st) * 64 + bg) * 16 + hi * 4] = st4;
}

// -------- reduce partials over st (8), squash over d, write v/out --------
__global__ __launch_bounds__(256) void squash_v_kernel(const float* __restrict__ sp,
        float* __restrict__ dest) {
    const int t = blockIdx.x * 256 + threadIdx.x;
    const int d = t & 15;
    const int cap = t >> 4;
    const int o = cap >> 6;
    const int bb = cap & 63;
    float s = 0.f;
    #pragma unroll
    for (int st = 0; st < 8; ++st)
        s += sp[(((size_t)o * 8 + st) * 64 + bb) * 16 + d];
    float s2 = s * s;
    #pragma unroll
    for (int off = 1; off < 16; off <<= 1)
        s2 += __shfl_xor(s2, off, 16);
    float scale = (s2 / (1.f + s2)) / sqrtf(s2 + 1e-8f);
    dest[(bb * NO + o) * ND + d] = s * scale;
}

// ---- r_logits via MFMA: per-o GEMM G[(i,k) x b] = [Wh|Wl] · [v...]; then
// in-register k-reduce with ut.
template <int ADD>
__global__ __launch_bounds__(256) void r_logits_mfma_kernel(
        const float* __restrict__ W, const float* __restrict__ ut,
        const float* __restrict__ v, float* __restrict__ bbuf) {
    const int o = blockIdx.x;
    const int st = blockIdx.y;               // 128 i per block
    __shared__ __align__(16) unsigned short Aext[128 * 40];
    __shared__ __align__(16) unsigned short B1[64 * 40];
    __shared__ __align__(16) unsigned short B2[64 * 40];
    __shared__ float ul[128 * 66];
    const int tid = threadIdx.x;
    const int lane = tid & 63;
    const int w = tid >> 6;
    const int l15 = lane & 15;
    const int hi = lane >> 4;
    const float* Wo = W + (size_t)o * 262144;
    {
        const int b = tid >> 2;
        const int dq = (tid & 3) * 4;
        float4 vv = *(const float4*)&v[((size_t)b * NO + o) * ND + dq];
        float q[4] = {vv.x, vv.y, vv.z, vv.w};
        #pragma unroll
        for (int c = 0; c < 4; ++c) {
            unsigned short h = f2bf(q[c]);
            unsigned short l = f2bf(q[c] - bf2f(h));
            B1[b * 40 + dq + c] = h;
            B1[b * 40 + 16 + dq + c] = h;
            B2[b * 40 + dq + c] = l;
            B2[b * 40 + 16 + dq + c] = 0;
        }
    }
    __syncthreads();
    #pragma unroll 1
    for (int iter = 0; iter < 8; ++iter) {
        __syncthreads();
        #pragma unroll
        for (int rep = 0; rep < 2; ++rep) {
            const int slot = rep * 256 + tid;
            const int i_l = slot >> 5;
            const int dgrp = (slot >> 3) & 3;
            const int k = slot & 7;
            const float* src = Wo + (size_t)(st * 128 + iter * 16 + i_l) * 128
                             + dgrp * 32 + k;
            float v0 = src[0], v1 = src[8], v2 = src[16], v3 = src[24];
            unsigned short h0 = f2bf(v0), l0 = f2bf(v0 - bf2f(h0));
            unsigned short h1 = f2bf(v1), l1 = f2bf(v1 - bf2f(h1));
            unsigned short h2 = f2bf(v2), l2 = f2bf(v2 - bf2f(h2));
            unsigned short h3 = f2bf(v3), l3 = f2bf(v3 - bf2f(h3));
            uint2 ph; ph.x = h0 | ((unsigned)h1 << 16); ph.y = h2 | ((unsigned)h3 << 16);
            uint2 pl; pl.x = l0 | ((unsigned)l1 << 16); pl.y = l2 | ((unsigned)l3 << 16);
            unsigned short* dst = Aext + (i_l * 8 + k) * 40 + dgrp * 4;
            *(uint2*)dst = ph;
            *(uint2*)(dst + 16) = pl;
        }
        const int base_row = (st * 128 + iter * 16) * 8;
        #pragma unroll
        for (int rep = 0; rep < 8; ++rep) {
            const int idx = tid + 256 * rep;
            const int row = idx >> 4, bq = idx & 15;
            float4 uv = *(const float4*)(ut + (size_t)(base_row + row) * 64 + 4 * bq);
            *(float4*)&ul[row * 66 + 4 * bq] = uv;
        }
        __syncthreads();
        f32x4 acc[8];
        bf16x8 bf1 = *(const bf16x8*)&B1[(w * 16 + l15) * 40 + hi * 8];
        bf16x8 bf2 = *(const bf16x8*)&B2[(w * 16 + l15) * 40 + hi * 8];
        #pragma unroll
        for (int mt = 0; mt < 8; ++mt) {
            f32x4 z = {0.f, 0.f, 0.f, 0.f};
            bf16x8 af = *(const bf16x8*)&Aext[(mt * 16 + l15) * 40 + hi * 8];
            z = __builtin_amdgcn_mfma_f32_16x16x32_bf16(af, bf1, z, 0, 0, 0);
            z = __builtin_amdgcn_mfma_f32_16x16x32_bf16(af, bf2, z, 0, 0, 0);
            acc[mt] = z;
        }
        #pragma unroll
        for (int mt = 0; mt < 8; ++mt) {
            float partial = 0.f;
            #pragma unroll
            for (int r = 0; r < 4; ++r) {
                const int grow = mt * 16 + hi * 4 + r;
                partial = fmaf(acc[mt][r], ul[grow * 66 + w * 16 + l15], partial);
            }
            float sum = partial + __shfl_xor(partial, 16);
            if ((hi & 1) == 0) {
                const int i_glob = st * 128 + iter * 16 + mt * 2 + (hi >> 1);
                const int bg = w * 16 + l15;
                const size_t addr = (size_t)bg * (NO * NI) + (size_t)o * NI + i_glob;
                bbuf[addr] = (ADD ? bbuf[addr] : 0.f) + sum;
            }
        }
    }
}

// -------- softmax over o (axis=1): register-resident column (1 read + 1 write) --
// r20: old version made 3 strided passes (208 MB/launch). vals[100] fully
// unrolled -> static indices -> VGPRs (rule: no runtime-indexed arrays).
__global__ __launch_bounds__(256) void softmax_kernel(const float* __restrict__ bbuf,
        float* __restrict__ cbuf) {
    const int bb = blockIdx.x >> 3;
    const int i = (blockIdx.x & 7) * 256 + threadIdx.x;
    const float* col = bbuf + (size_t)bb * (NO * NI) + i;
    float vals[NO];
    float m = -1e30f;
    #pragma unroll
    for (int o = 0; o < NO; ++o) {
        vals[o] = col[(size_t)o * NI];
        m = fmaxf(m, vals[o]);
    }
    float s = 0.f;
    #pragma unroll
    for (int o = 0; o < NO; ++o) {
        vals[o] = __expf(vals[o] - m);
        s += vals[o];
    }
    const float inv = 1.f / s;
    float* outp = cbuf + (size_t)bb * (NO * NI) + i;
    #pragma unroll
    for (int o = 0; o < NO; ++o)
        outp[(size_t)o * NI] = vals[o] * inv;
}

extern "C" void kernel_launch(void* const* d_in, const int* in_sizes, int n_in,
                              void* d_out, int out_size, void* d_ws, size_t ws_size,
                              hipStream_t stream) {
    (void)in_sizes; (void)n_in; (void)out_size; (void)ws_size;
    const float* x      = (const float*)d_in[0];
    const float* conv_w = (const float*)d_in[1];
    const float* conv_b = (const float*)d_in[2];
    const float* pcap_w = (const float*)d_in[3];
    const float* pcap_b = (const float*)d_in[4];
    const float* W      = (const float*)d_in[5];
    float* out = (float*)d_out;
    float* ws  = (float*)d_ws;
    unsigned short* h_hi = (unsigned short*)(ws + WS_H);
    unsigned short* h_lo = h_hi + 9437184;
    unsigned short* w2hi = (unsigned short*)(ws + WS_CB);   // 256*256*96 = 6291456
    unsigned short* w2lo = w2hi + 6291456;
    float* ut  = ws + WS_H;    // overlaps h (dead after conv2)
    float* u   = ws + WS_U;
    float* bbf = ws + WS_BB;
    float* cbf = ws + WS_CB;
    float* sp  = ws + WS_SP;
    float* v   = ws + WS_V;
    float* pp  = ws + WS_PP;

    wb_precompute_kernel<<<dim3(256, 4), 256, 0, stream>>>(pcap_w, w2hi, w2lo);
    conv1_kernel<<<dim3(64, 16), 256, 0, stream>>>(x, conv_w, conv_b, h_hi, h_lo);
    conv2_mfma_kernel<<<dim3(32, 2, 8), 256, 0, stream>>>(h_hi, h_lo, w2hi, w2lo, pp);
    reduce_bias_squash_kernel<<<512, 256, 0, stream>>>(pp, pcap_b, u);
    transpose_u_kernel<<<128, 256, 0, stream>>>(u, ut);
    // routing iter 0 (c uniform = 1/100)
    r_weighted_mfma_kernel<1><<<dim3(100, 8), 256, 0, stream>>>(W, u, nullptr, sp);
    squash_v_kernel<<<400, 256, 0, stream>>>(sp, v);
    r_logits_mfma_kernel<0><<<dim3(100, 16), 256, 0, stream>>>(W, ut, v, bbf);
    // routing iter 1
    softmax_kernel<<<512, 256, 0, stream>>>(bbf, cbf);
    r_weighted_mfma_kernel<0><<<dim3(100, 8), 256, 0, stream>>>(W, u, cbf, sp);
    squash_v_kernel<<<400, 256, 0, stream>>>(sp, v);
    r_logits_mfma_kernel<1><<<dim3(100, 16), 256, 0, stream>>>(W, ut, v, bbf);
    // routing iter 2
    softmax_kernel<<<512, 256, 0, stream>>>(bbf, cbf);
    r_weighted_mfma_kernel<0><<<dim3(100, 8), 256, 0, stream>>>(W, u, cbf, sp);
    squash_v_kernel<<<400, 256, 0, stream>>>(sp, out);
}

// Round 23
// 741.232 us; speedup vs baseline: 1.3144x; 1.0004x over previous
//
#include <hip/hip_runtime.h>

#define NB 64
#define NO 100
#define NI 2048
#define ND 16
#define NK 8

// ws layout (float offsets)
#define WS_H    0            // h_hi/h_lo (conv phase); ut [16384][64] (routing phase)
#define WS_U    9437184      // u: 64*2048*8 = 1048576
#define WS_BB   10485760     // b logits: 13107200 (pp overlaps here pre-routing)
#define WS_CB   23592960     // c: 13107200 (w2 hi/lo overlap here pre-routing)
#define WS_SP   36700160     // s partials: 100*8*64*16 = 819200
#define WS_V    38338560     // v: 102400
#define WS_PP   WS_BB        // conv2 partials: 8*64*256*64 = 8388608 floats

typedef __attribute__((ext_vector_type(8))) short bf16x8;
typedef __attribute__((ext_vector_type(16))) float f32x16;
typedef __attribute__((ext_vector_type(4))) float f32x4;

__device__ inline unsigned short f2bf(float x) {   // RNE float->bf16
    union { float f; unsigned u; } v; v.f = x;
    unsigned r = (v.u + 0x7FFFu + ((v.u >> 16) & 1u)) >> 16;
    return (unsigned short)r;
}
__device__ inline float bf2f(unsigned short h) {
    union { unsigned u; float f; } v; v.u = ((unsigned)h) << 16;
    return v.f;
}

// ---------------- conv1: [64,3,32,32] -> relu -> h_hi/h_lo bf16 ----------------
__global__ __launch_bounds__(256) void conv1_kernel(const float* __restrict__ x,
        const float* __restrict__ w, const float* __restrict__ bias,
        unsigned short* __restrict__ h_hi, unsigned short* __restrict__ h_lo) {
    const int b = blockIdx.x;
    const int ocg = blockIdx.y;
    __shared__ float xl[3 * 32 * 32];
    __shared__ float wl[16 * 243];
    const int tid = threadIdx.x;
    for (int idx = tid; idx < 3072; idx += 256) xl[idx] = x[b * 3072 + idx];
    for (int idx = tid; idx < 16 * 243; idx += 256)
        wl[idx] = w[ocg * 16 * 243 + idx];
    __syncthreads();
    const int lane = tid & 63;
    const int wg = tid >> 6;
    float acc[4][9];
    #pragma unroll
    for (int jj = 0; jj < 4; ++jj) {
        float bv = bias[ocg * 16 + wg * 4 + jj];
        #pragma unroll
        for (int j = 0; j < 9; ++j) acc[jj][j] = bv;
    }
    int xbase[9];
    #pragma unroll
    for (int j = 0; j < 9; ++j) {
        int p = lane + 64 * j;
        xbase[j] = (p / 24) * 32 + (p % 24);
    }
    for (int ic = 0; ic < 3; ++ic)
        for (int ky = 0; ky < 9; ++ky) {
            #pragma unroll
            for (int kx = 0; kx < 9; ++kx) {
                float wv[4];
                #pragma unroll
                for (int jj = 0; jj < 4; ++jj)
                    wv[jj] = wl[(wg * 4 + jj) * 243 + ic * 81 + ky * 9 + kx];
                #pragma unroll
                for (int j = 0; j < 9; ++j) {
                    float xv = xl[ic * 1024 + xbase[j] + ky * 32 + kx];
                    #pragma unroll
                    for (int jj = 0; jj < 4; ++jj)
                        acc[jj][j] = fmaf(xv, wv[jj], acc[jj][j]);
                }
            }
        }
    #pragma unroll
    for (int jj = 0; jj < 4; ++jj) {
        int oc = ocg * 16 + wg * 4 + jj;
        #pragma unroll
        for (int j = 0; j < 9; ++j) {
            int p = lane + 64 * j;
            float v = fmaxf(acc[jj][j], 0.f);
            unsigned short hi = f2bf(v);
            unsigned short lo = f2bf(v - bf2f(hi));
            size_t o = (size_t)(b * 256 + oc) * 576 + p;
            h_hi[o] = hi;
            h_lo[o] = lo;
        }
    }
}

// ---- precompute w2_hi/lo[ic][oc][96] bf16, k' = ky*10+kx (kx=9, k'>=90 pad=0) ----
__global__ __launch_bounds__(256) void wb_precompute_kernel(const float* __restrict__ w,
        unsigned short* __restrict__ w2hi, unsigned short* __restrict__ w2lo) {
    const int ic = blockIdx.x;           // 0..255
    const int ocq = blockIdx.y;          // 0..3 (64 oc)
    __shared__ float tl[64][85];
    const int tid = threadIdx.x;
    for (int f = tid; f < 5184; f += 256) {
        int oc = f / 81, kk = f % 81;
        tl[oc][kk] = w[(size_t)(ocq * 64 + oc) * 20736 + ic * 81 + kk];
    }
    __syncthreads();
    for (int idx = tid; idx < 6144; idx += 256) {   // 64 oc x 96 k'
        int oc = idx / 96;
        int kp = idx % 96;
        int ky = kp / 10, kx = kp % 10;
        float val = (ky < 9 && kx < 9) ? tl[oc][ky * 9 + kx] : 0.f;
        unsigned short hi = f2bf(val);
        unsigned short lo = f2bf(val - bf2f(hi));
        size_t dst = ((size_t)ic * 256 + ocq * 64 + oc) * 96 + kp;
        w2hi[dst] = hi;
        w2lo[dst] = lo;
    }
}

// ---- conv2 via MFMA (split-bf16), v7: dense k-pack 96, per-ic B stage ----
// At MFMA floor (192us, pipe-busy ~65us vs 61us dense floor). FROZEN.
__global__ __launch_bounds__(256) void conv2_mfma_kernel(
        const unsigned short* __restrict__ h_hi, const unsigned short* __restrict__ h_lo,
        const unsigned short* __restrict__ w2hi, const unsigned short* __restrict__ w2lo,
        float* __restrict__ pp) {
    const int bpair = blockIdx.x;        // 0..31
    const int ocb = blockIdx.y;          // 0..1  (128 oc)
    const int ks = blockIdx.z;           // 0..7  (32 ic)
    __shared__ __align__(16) unsigned short Bh[128 * 100];
    __shared__ __align__(16) unsigned short Bl[128 * 100];
    const int tid = threadIdx.x;
    const int lane = tid & 63;
    const int wid = tid >> 6;
    const int wr = wid >> 1, wc = wid & 1;
    const int l31 = lane & 31, kh = lane >> 5;
    const int slot = tid & 127;
    const int role = tid >> 7;
    const int oy = (slot >> 3) & 7;
    const int ox = slot & 7;
    const unsigned short* hsel = role ? h_lo : h_hi;
    const size_t hrow0 = ((size_t)(bpair * 2 + (slot >> 6)) * 256) * 576;
    const int ic0 = ks * 32;

    {
        unsigned int* Bz = (unsigned int*)((role ? Bl : Bh) + slot * 100 + 90);
        #pragma unroll
        for (int j = 0; j < 5; ++j) Bz[j] = 0u;
    }

    f32x16 acc[2][2];
    #pragma unroll
    for (int m = 0; m < 2; ++m)
        #pragma unroll
        for (int n = 0; n < 2; ++n)
            #pragma unroll
            for (int r = 0; r < 16; ++r) acc[m][n][r] = 0.f;

#define LDS64(arr, off, dst) { union { struct { uint2 a, b; } p; bf16x8 v; } u_;           \
    u_.p.a = *(const uint2*)((arr) + (off));                                               \
    u_.p.b = *(const uint2*)((arr) + (off) + 4);                                           \
    dst = u_.v; }

    #pragma unroll 1
    for (int ic_l = 0; ic_l < 32; ++ic_l) {
        const int ic = ic0 + ic_l;
        __syncthreads();
        {
            const size_t h_ic = hrow0 + (size_t)ic * 576;
            unsigned int* Brow = (unsigned int*)((role ? Bl : Bh) + slot * 100);
            #pragma unroll
            for (int ky = 0; ky < 9; ++ky) {
                const unsigned int* hp =
                    (const unsigned int*)(hsel + h_ic + (2 * oy + ky) * 24 + 2 * ox);
                unsigned int* dst = Brow + 5 * ky;
                dst[0] = hp[0]; dst[1] = hp[1]; dst[2] = hp[2];
                dst[3] = hp[3]; dst[4] = hp[4];
            }
        }
        __syncthreads();
        const size_t wbase = ((size_t)ic * 256 + ocb * 128) * 96;
        #pragma unroll
        for (int c = 0; c < 6; ++c) {
            const size_t a0 = wbase + (size_t)(wr * 64 + l31) * 96 + 16 * c + 8 * kh;
            const size_t a1 = a0 + 32 * 96;
            bf16x8 ah0 = *(const bf16x8*)(w2hi + a0);
            bf16x8 ah1 = *(const bf16x8*)(w2hi + a1);
            bf16x8 al0 = *(const bf16x8*)(w2lo + a0);
            bf16x8 al1 = *(const bf16x8*)(w2lo + a1);
            bf16x8 bh0, bh1, bl0, bl1;
            const int b0 = (wc * 64 + l31) * 100 + 16 * c + 8 * kh;
            const int b1 = b0 + 32 * 100;
            LDS64(Bh, b0, bh0); LDS64(Bh, b1, bh1);
            LDS64(Bl, b0, bl0); LDS64(Bl, b1, bl1);
            acc[0][0] = __builtin_amdgcn_mfma_f32_32x32x16_bf16(ah0, bh0, acc[0][0], 0, 0, 0);
            acc[0][0] = __builtin_amdgcn_mfma_f32_32x32x16_bf16(ah0, bl0, acc[0][0], 0, 0, 0);
            acc[0][0] = __builtin_amdgcn_mfma_f32_32x32x16_bf16(al0, bh0, acc[0][0], 0, 0, 0);
            acc[0][1] = __builtin_amdgcn_mfma_f32_32x32x16_bf16(ah0, bh1, acc[0][1], 0, 0, 0);
            acc[0][1] = __builtin_amdgcn_mfma_f32_32x32x16_bf16(ah0, bl1, acc[0][1], 0, 0, 0);
            acc[0][1] = __builtin_amdgcn_mfma_f32_32x32x16_bf16(al0, bh1, acc[0][1], 0, 0, 0);
            acc[1][0] = __builtin_amdgcn_mfma_f32_32x32x16_bf16(ah1, bh0, acc[1][0], 0, 0, 0);
            acc[1][0] = __builtin_amdgcn_mfma_f32_32x32x16_bf16(ah1, bl0, acc[1][0], 0, 0, 0);
            acc[1][0] = __builtin_amdgcn_mfma_f32_32x32x16_bf16(al1, bh0, acc[1][0], 0, 0, 0);
            acc[1][1] = __builtin_amdgcn_mfma_f32_32x32x16_bf16(ah1, bh1, acc[1][1], 0, 0, 0);
            acc[1][1] = __builtin_amdgcn_mfma_f32_32x32x16_bf16(ah1, bl1, acc[1][1], 0, 0, 0);
            acc[1][1] = __builtin_amdgcn_mfma_f32_32x32x16_bf16(al1, bh1, acc[1][1], 0, 0, 0);
        }
    }
#undef LDS64
    #pragma unroll
    for (int m = 0; m < 2; ++m)
        #pragma unroll
        for (int n = 0; n < 2; ++n) {
            const int slotg = wc * 64 + n * 32 + l31;
            const int b = bpair * 2 + (slotg >> 6);
            const int pos = slotg & 63;
            #pragma unroll
            for (int r = 0; r < 16; ++r) {
                const int row = (r & 3) + 8 * (r >> 2) + 4 * kh;
                const int oc = ocb * 128 + wr * 64 + m * 32 + row;
                pp[(((size_t)ks * 64 + b) * 256 + oc) * 64 + pos] = acc[m][n][r];
            }
        }
}

// -------- reduce partials over ks, +bias, squash capsule rows of 8 -> u --------
__global__ __launch_bounds__(256) void reduce_bias_squash_kernel(
        const float* __restrict__ pp, const float* __restrict__ bias,
        float* __restrict__ u) {
    const int cap = blockIdx.x * 256 + threadIdx.x;
    const int b = cap >> 11;
    const int rem = cap & 2047;
    const int oc = rem >> 3;
    const int oy = rem & 7;
    float4 sa = {0.f, 0.f, 0.f, 0.f}, sb = {0.f, 0.f, 0.f, 0.f};
    #pragma unroll
    for (int ks = 0; ks < 8; ++ks) {
        const float4* p4 = (const float4*)&pp[(((size_t)ks * 64 + b) * 256 + oc) * 64 + oy * 8];
        float4 a = p4[0], c = p4[1];
        sa.x += a.x; sa.y += a.y; sa.z += a.z; sa.w += a.w;
        sb.x += c.x; sb.y += c.y; sb.z += c.z; sb.w += c.w;
    }
    const float bv = bias[oc];
    sa.x += bv; sa.y += bv; sa.z += bv; sa.w += bv;
    sb.x += bv; sb.y += bv; sb.z += bv; sb.w += bv;
    float s2 = sa.x * sa.x + sa.y * sa.y + sa.z * sa.z + sa.w * sa.w
             + sb.x * sb.x + sb.y * sb.y + sb.z * sb.z + sb.w * sb.w;
    float scale = (s2 / (1.f + s2)) / sqrtf(s2 + 1e-8f);
    sa.x *= scale; sa.y *= scale; sa.z *= scale; sa.w *= scale;
    sb.x *= scale; sb.y *= scale; sb.z *= scale; sb.w *= scale;
    float4* up = (float4*)&u[(size_t)cap * 8];
    up[0] = sa;
    up[1] = sb;
}

// -------- transpose u -> ut[(i*8+k)][b] (once per launch; u fixed in routing) ----
__global__ __launch_bounds__(256) void transpose_u_kernel(const float* __restrict__ u,
        float* __restrict__ ut) {
    const int blk = blockIdx.x;          // 128 blocks x 128 (i,k)-rows
    __shared__ float tl[64 * 132];
    const int tid = threadIdx.x;
    #pragma unroll
    for (int rep = 0; rep < 8; ++rep) {
        const int idx = tid + 256 * rep;        // 0..2047 float4s
        const int b = idx >> 5, q = idx & 31;
        float4 uv = *(const float4*)(u + (size_t)b * 16384 + blk * 128 + 4 * q);
        *(float4*)&tl[b * 132 + 4 * q] = uv;
    }
    __syncthreads();
    #pragma unroll
    for (int rep = 0; rep < 32; ++rep) {
        const int row = rep * 4 + (tid >> 6);
        const int b = tid & 63;
        ut[(size_t)(blk * 128 + row) * 64 + b] = tl[b * 132 + row];
    }
}

// ---- r_weighted via MFMA: per-o GEMM C[16d x 64b] = W[o]^T · (c ⊙ u) ----
template <int UNIFORM>
__global__ __launch_bounds__(256) void r_weighted_mfma_kernel(
        const float* __restrict__ W, const float* __restrict__ u,
        const float* __restrict__ cbuf, float* __restrict__ sp) {
    const int o = blockIdx.x;
    const int st = blockIdx.y;
    __shared__ __align__(16) unsigned short Ahi[16 * 72];
    __shared__ __align__(16) unsigned short Alo[16 * 72];
    __shared__ __align__(16) unsigned short Bhi[64 * 72];
    __shared__ __align__(16) unsigned short Blo[64 * 72];
    const int tid = threadIdx.x;
    const int lane = tid & 63;
    const int w = tid >> 6;
    const int l15 = lane & 15;
    const int hi = lane >> 4;
    const int sb = tid >> 2;
    const int si = tid & 3;
    f32x4 acc = {0.f, 0.f, 0.f, 0.f};
    const float* Wo = W + (size_t)o * 262144;
    const int i_base = st * 256;
    #pragma unroll 1
    for (int iter = 0; iter < 32; ++iter) {
        const int i0 = i_base + iter * 8;
        __syncthreads();
        {
            float4 wv = *(const float4*)(Wo + (size_t)i0 * 128 + 4 * tid);
            const int i_l = tid >> 5;
            const int d = (tid >> 1) & 15;
            const int k0 = (tid & 1) * 4;
            unsigned short* dh = Ahi + d * 72 + i_l * 8 + k0;
            unsigned short* dl = Alo + d * 72 + i_l * 8 + k0;
            float vv[4] = {wv.x, wv.y, wv.z, wv.w};
            unsigned int h01, h23, l01, l23;
            unsigned short h, l;
            h = f2bf(vv[0]); l = f2bf(vv[0] - bf2f(h)); h01 = h; l01 = l;
            h = f2bf(vv[1]); l = f2bf(vv[1] - bf2f(h)); h01 |= (unsigned)h << 16; l01 |= (unsigned)l << 16;
            h = f2bf(vv[2]); l = f2bf(vv[2] - bf2f(h)); h23 = h; l23 = l;
            h = f2bf(vv[3]); l = f2bf(vv[3] - bf2f(h)); h23 |= (unsigned)h << 16; l23 |= (unsigned)l << 16;
            *(unsigned int*)dh = h01; *(unsigned int*)(dh + 2) = h23;
            *(unsigned int*)dl = l01; *(unsigned int*)(dl + 2) = l23;
        }
        #pragma unroll
        for (int half = 0; half < 2; ++half) {
            const int i_l = si + 4 * half;
            const float* up = u + (size_t)sb * 16384 + (size_t)(i0 + i_l) * 8;
            float4 u0 = *(const float4*)up;
            float4 u1 = *(const float4*)(up + 4);
            float cv = UNIFORM ? 0.01f
                               : cbuf[(size_t)sb * (NO * NI) + o * NI + i0 + i_l];
            float q[8] = {u0.x * cv, u0.y * cv, u0.z * cv, u0.w * cv,
                          u1.x * cv, u1.y * cv, u1.z * cv, u1.w * cv};
            uint4 ph, pl;
            unsigned short h0, h1, l0, l1;
            h0 = f2bf(q[0]); l0 = f2bf(q[0] - bf2f(h0));
            h1 = f2bf(q[1]); l1 = f2bf(q[1] - bf2f(h1));
            ph.x = h0 | ((unsigned)h1 << 16); pl.x = l0 | ((unsigned)l1 << 16);
            h0 = f2bf(q[2]); l0 = f2bf(q[2] - bf2f(h0));
            h1 = f2bf(q[3]); l1 = f2bf(q[3] - bf2f(h1));
            ph.y = h0 | ((unsigned)h1 << 16); pl.y = l0 | ((unsigned)l1 << 16);
            h0 = f2bf(q[4]); l0 = f2bf(q[4] - bf2f(h0));
            h1 = f2bf(q[5]); l1 = f2bf(q[5] - bf2f(h1));
            ph.z = h0 | ((unsigned)h1 << 16); pl.z = l0 | ((unsigned)l1 << 16);
            h0 = f2bf(q[6]); l0 = f2bf(q[6] - bf2f(h0));
            h1 = f2bf(q[7]); l1 = f2bf(q[7] - bf2f(h1));
            ph.w = h0 | ((unsigned)h1 << 16); pl.w = l0 | ((unsigned)l1 << 16);
            *(uint4*)(Bhi + sb * 72 + i_l * 8) = ph;
            *(uint4*)(Blo + sb * 72 + i_l * 8) = pl;
        }
        __syncthreads();
        #pragma unroll
        for (int ch = 0; ch < 2; ++ch) {
            bf16x8 ah = *(const bf16x8*)(Ahi + l15 * 72 + ch * 32 + hi * 8);
            bf16x8 al = *(const bf16x8*)(Alo + l15 * 72 + ch * 32 + hi * 8);
            bf16x8 bh = *(const bf16x8*)(Bhi + (w * 16 + l15) * 72 + ch * 32 + hi * 8);
            bf16x8 bl = *(const bf16x8*)(Blo + (w * 16 + l15) * 72 + ch * 32 + hi * 8);
            acc = __builtin_amdgcn_mfma_f32_16x16x32_bf16(ah, bh, acc, 0, 0, 0);
            acc = __builtin_amdgcn_mfma_f32_16x16x32_bf16(ah, bl, acc, 0, 0, 0);
            acc = __builtin_amdgcn_mfma_f32_16x16x32_bf16(al, bh, acc, 0, 0, 0);
        }
    }
    const int bg = w * 16 + l15;
    float4 st4;
    st4.x = acc[0]; st4.y = acc[1]; st4.z = acc[2]; st4.w = acc[3];
    *(float4*)&sp[(((size_t)o * 8 + st) * 64 + bg) * 16 + hi * 4] = st4;
}

// -------- reduce partials over st (8), squash over d, write v/out --------
__global__ __launch_bounds__(256) void squash_v_kernel(const float* __restrict__ sp,
        float* __restrict__ dest) {
    const int t = blockIdx.x * 256 + threadIdx.x;
    const int d = t & 15;
    const int cap = t >> 4;
    const int o = cap >> 6;
    const int bb = cap & 63;
    float s = 0.f;
    #pragma unroll
    for (int st = 0; st < 8; ++st)
        s += sp[(((size_t)o * 8 + st) * 64 + bb) * 16 + d];
    float s2 = s * s;
    #pragma unroll
    for (int off = 1; off < 16; off <<= 1)
        s2 += __shfl_xor(s2, off, 16);
    float scale = (s2 / (1.f + s2)) / sqrtf(s2 + 1e-8f);
    dest[(bb * NO + o) * ND + d] = s * scale;
}

// ---- r_logits via MFMA: per-o GEMM G[(i,k) x b] = [Wh|Wl] · [v...]; then
// in-register k-reduce with ut.
template <int ADD>
__global__ __launch_bounds__(256) void r_logits_mfma_kernel(
        const float* __restrict__ W, const float* __restrict__ ut,
        const float* __restrict__ v, float* __restrict__ bbuf) {
    const int o = blockIdx.x;
    const int st = blockIdx.y;               // 128 i per block
    __shared__ __align__(16) unsigned short Aext[128 * 40];
    __shared__ __align__(16) unsigned short B1[64 * 40];
    __shared__ __align__(16) unsigned short B2[64 * 40];
    __shared__ float ul[128 * 66];
    const int tid = threadIdx.x;
    const int lane = tid & 63;
    const int w = tid >> 6;
    const int l15 = lane & 15;
    const int hi = lane >> 4;
    const float* Wo = W + (size_t)o * 262144;
    {
        const int b = tid >> 2;
        const int dq = (tid & 3) * 4;
        float4 vv = *(const float4*)&v[((size_t)b * NO + o) * ND + dq];
        float q[4] = {vv.x, vv.y, vv.z, vv.w};
        #pragma unroll
        for (int c = 0; c < 4; ++c) {
            unsigned short h = f2bf(q[c]);
            unsigned short l = f2bf(q[c] - bf2f(h));
            B1[b * 40 + dq + c] = h;
            B1[b * 40 + 16 + dq + c] = h;
            B2[b * 40 + dq + c] = l;
            B2[b * 40 + 16 + dq + c] = 0;
        }
    }
    __syncthreads();
    #pragma unroll 1
    for (int iter = 0; iter < 8; ++iter) {
        __syncthreads();
        #pragma unroll
        for (int rep = 0; rep < 2; ++rep) {
            const int slot = rep * 256 + tid;
            const int i_l = slot >> 5;
            const int dgrp = (slot >> 3) & 3;
            const int k = slot & 7;
            const float* src = Wo + (size_t)(st * 128 + iter * 16 + i_l) * 128
                             + dgrp * 32 + k;
            float v0 = src[0], v1 = src[8], v2 = src[16], v3 = src[24];
            unsigned short h0 = f2bf(v0), l0 = f2bf(v0 - bf2f(h0));
            unsigned short h1 = f2bf(v1), l1 = f2bf(v1 - bf2f(h1));
            unsigned short h2 = f2bf(v2), l2 = f2bf(v2 - bf2f(h2));
            unsigned short h3 = f2bf(v3), l3 = f2bf(v3 - bf2f(h3));
            uint2 ph; ph.x = h0 | ((unsigned)h1 << 16); ph.y = h2 | ((unsigned)h3 << 16);
            uint2 pl; pl.x = l0 | ((unsigned)l1 << 16); pl.y = l2 | ((unsigned)l3 << 16);
            unsigned short* dst = Aext + (i_l * 8 + k) * 40 + dgrp * 4;
            *(uint2*)dst = ph;
            *(uint2*)(dst + 16) = pl;
        }
        const int base_row = (st * 128 + iter * 16) * 8;
        #pragma unroll
        for (int rep = 0; rep < 8; ++rep) {
            const int idx = tid + 256 * rep;
            const int row = idx >> 4, bq = idx & 15;
            float4 uv = *(const float4*)(ut + (size_t)(base_row + row) * 64 + 4 * bq);
            *(float4*)&ul[row * 66 + 4 * bq] = uv;
        }
        __syncthreads();
        f32x4 acc[8];
        bf16x8 bf1 = *(const bf16x8*)&B1[(w * 16 + l15) * 40 + hi * 8];
        bf16x8 bf2 = *(const bf16x8*)&B2[(w * 16 + l15) * 40 + hi * 8];
        #pragma unroll
        for (int mt = 0; mt < 8; ++mt) {
            f32x4 z = {0.f, 0.f, 0.f, 0.f};
            bf16x8 af = *(const bf16x8*)&Aext[(mt * 16 + l15) * 40 + hi * 8];
            z = __builtin_amdgcn_mfma_f32_16x16x32_bf16(af, bf1, z, 0, 0, 0);
            z = __builtin_amdgcn_mfma_f32_16x16x32_bf16(af, bf2, z, 0, 0, 0);
            acc[mt] = z;
        }
        #pragma unroll
        for (int mt = 0; mt < 8; ++mt) {
            float partial = 0.f;
            #pragma unroll
            for (int r = 0; r < 4; ++r) {
                const int grow = mt * 16 + hi * 4 + r;
                partial = fmaf(acc[mt][r], ul[grow * 66 + w * 16 + l15], partial);
            }
            float sum = partial + __shfl_xor(partial, 16);
            if ((hi & 1) == 0) {
                const int i_glob = st * 128 + iter * 16 + mt * 2 + (hi >> 1);
                const int bg = w * 16 + l15;
                const size_t addr = (size_t)bg * (NO * NI) + (size_t)o * NI + i_glob;
                bbuf[addr] = (ADD ? bbuf[addr] : 0.f) + sum;
            }
        }
    }
}

// -------- softmax over o (axis=1): register-resident column (1 read + 1 write) --
__global__ __launch_bounds__(256) void softmax_kernel(const float* __restrict__ bbuf,
        float* __restrict__ cbuf) {
    const int bb = blockIdx.x >> 3;
    const int i = (blockIdx.x & 7) * 256 + threadIdx.x;
    const float* col = bbuf + (size_t)bb * (NO * NI) + i;
    float vals[NO];
    float m = -1e30f;
    #pragma unroll
    for (int o = 0; o < NO; ++o) {
        vals[o] = col[(size_t)o * NI];
        m = fmaxf(m, vals[o]);
    }
    float s = 0.f;
    #pragma unroll
    for (int o = 0; o < NO; ++o) {
        vals[o] = __expf(vals[o] - m);
        s += vals[o];
    }
    const float inv = 1.f / s;
    float* outp = cbuf + (size_t)bb * (NO * NI) + i;
    #pragma unroll
    for (int o = 0; o < NO; ++o)
        outp[(size_t)o * NI] = vals[o] * inv;
}

extern "C" void kernel_launch(void* const* d_in, const int* in_sizes, int n_in,
                              void* d_out, int out_size, void* d_ws, size_t ws_size,
                              hipStream_t stream) {
    (void)in_sizes; (void)n_in; (void)out_size; (void)ws_size;
    const float* x      = (const float*)d_in[0];
    const float* conv_w = (const float*)d_in[1];
    const float* conv_b = (const float*)d_in[2];
    const float* pcap_w = (const float*)d_in[3];
    const float* pcap_b = (const float*)d_in[4];
    const float* W      = (const float*)d_in[5];
    float* out = (float*)d_out;
    float* ws  = (float*)d_ws;
    unsigned short* h_hi = (unsigned short*)(ws + WS_H);
    unsigned short* h_lo = h_hi + 9437184;
    unsigned short* w2hi = (unsigned short*)(ws + WS_CB);   // 256*256*96 = 6291456
    unsigned short* w2lo = w2hi + 6291456;
    float* ut  = ws + WS_H;    // overlaps h (dead after conv2)
    float* u   = ws + WS_U;
    float* bbf = ws + WS_BB;
    float* cbf = ws + WS_CB;
    float* sp  = ws + WS_SP;
    float* v   = ws + WS_V;
    float* pp  = ws + WS_PP;

    wb_precompute_kernel<<<dim3(256, 4), 256, 0, stream>>>(pcap_w, w2hi, w2lo);
    conv1_kernel<<<dim3(64, 16), 256, 0, stream>>>(x, conv_w, conv_b, h_hi, h_lo);
    conv2_mfma_kernel<<<dim3(32, 2, 8), 256, 0, stream>>>(h_hi, h_lo, w2hi, w2lo, pp);
    reduce_bias_squash_kernel<<<512, 256, 0, stream>>>(pp, pcap_b, u);
    transpose_u_kernel<<<128, 256, 0, stream>>>(u, ut);
    // routing iter 0 (c uniform = 1/100)
    r_weighted_mfma_kernel<1><<<dim3(100, 8), 256, 0, stream>>>(W, u, nullptr, sp);
    squash_v_kernel<<<400, 256, 0, stream>>>(sp, v);
    r_logits_mfma_kernel<0><<<dim3(100, 16), 256, 0, stream>>>(W, ut, v, bbf);
    // routing iter 1
    softmax_kernel<<<512, 256, 0, stream>>>(bbf, cbf);
    r_weighted_mfma_kernel<0><<<dim3(100, 8), 256, 0, stream>>>(W, u, cbf, sp);
    squash_v_kernel<<<400, 256, 0, stream>>>(sp, v);
    r_logits_mfma_kernel<1><<<dim3(100, 16), 256, 0, stream>>>(W, ut, v, bbf);
    // routing iter 2
    softmax_kernel<<<512, 256, 0, stream>>>(bbf, cbf);
    r_weighted_mfma_kernel<0><<<dim3(100, 8), 256, 0, stream>>>(W, u, cbf, sp);
    squash_v_kernel<<<400, 256, 0, stream>>>(sp, out);
}